// Round 1
// baseline (1999.579 us; speedup 1.0000x reference)
//
#include <hip/hip_runtime.h>
#include <hip/hip_bf16.h>
#include <stdint.h>

// Problem constants (B,S,D,F,H fixed by the reference)
#define BB 2
#define SS 2048
#define DD 1024
#define FF 4096
#define HH 16
#define DKk 64
#define ROWS (BB*SS)   // 4096

typedef float f32x4 __attribute__((ext_vector_type(4)));
typedef __bf16 bf16x8 __attribute__((ext_vector_type(8)));

typedef __attribute__((address_space(1))) const void* gas1p;
typedef __attribute__((address_space(3))) void* las3p;

__device__ __forceinline__ void gload16(const void* g, void* l) {
    // wave-uniform LDS base; HW scatters lane i at base + i*16
    __builtin_amdgcn_global_load_lds((gas1p)g, (las3p)l, 16, 0, 0);
}

__device__ __forceinline__ unsigned short f2bf(float f) {
    unsigned int u = __builtin_bit_cast(unsigned int, f);
    u += 0x7fffu + ((u >> 16) & 1u);   // round-to-nearest-even
    return (unsigned short)(u >> 16);
}
__device__ __forceinline__ float bf2f(unsigned short s) {
    unsigned int u = ((unsigned int)s) << 16;
    return __builtin_bit_cast(float, u);
}
__device__ __forceinline__ float sigmoidf_(float x) { return 1.f / (1.f + __expf(-x)); }
__device__ __forceinline__ float siluf_(float x)    { return x / (1.f + __expf(-x)); }

// ---------------- transpose + fp32->bf16 convert: W[K][N] -> Wt[N][K] ----------------
__global__ __launch_bounds__(256) void transpose_cvt(const float* __restrict__ W,
                                                     unsigned short* __restrict__ Wt,
                                                     int K, int N) {
    __shared__ float tile[32][33];
    int tx = threadIdx.x & 31, ty = threadIdx.x >> 5; // ty 0..7
    int n0 = blockIdx.x * 32, k0 = blockIdx.y * 32;
#pragma unroll
    for (int i = 0; i < 4; ++i)
        tile[ty + 8 * i][tx] = W[(size_t)(k0 + ty + 8 * i) * N + n0 + tx];
    __syncthreads();
#pragma unroll
    for (int i = 0; i < 4; ++i)
        Wt[(size_t)(n0 + ty + 8 * i) * K + k0 + tx] = f2bf(tile[tx][ty + 8 * i]);
}

// ---------------- RMSNorm (D=1024) -> bf16 ----------------
__global__ __launch_bounds__(256) void rmsnorm_bf16_kernel(const float* __restrict__ src,
                                                           const float* __restrict__ w,
                                                           unsigned short* __restrict__ dst) {
    int row = blockIdx.x;
    int tid = threadIdx.x;
    float4 x = ((const float4*)(src + (size_t)row * DD))[tid];
    float ss = x.x * x.x + x.y * x.y + x.z * x.z + x.w * x.w;
#pragma unroll
    for (int m = 1; m < 64; m <<= 1) ss += __shfl_xor(ss, m, 64);
    __shared__ float ws4[4];
    if ((tid & 63) == 0) ws4[tid >> 6] = ss;
    __syncthreads();
    ss = ws4[0] + ws4[1] + ws4[2] + ws4[3];
    float sc = rsqrtf(ss * (1.f / DD) + 1e-6f);
    float4 wv = ((const float4*)w)[tid];
    ushort4 o;
    o.x = f2bf(x.x * sc * wv.x);
    o.y = f2bf(x.y * sc * wv.y);
    o.z = f2bf(x.z * sc * wv.z);
    o.w = f2bf(x.w * sc * wv.w);
    ((ushort4*)(dst + (size_t)row * DD))[tid] = o;
}

// ---------------- bf16 GEMM: C[M][N] = A[M][K] * Bt[N][K]^T (+ residual / bf16 out) ----------------
// EP 0: fp32 out; EP 1: fp32 out + fp32 residual; EP 2: bf16 out
#define BM 128
#define BN 128
#define BK 32

template <int EP>
__global__ __launch_bounds__(256) void gemm_bt(const unsigned short* __restrict__ A,
                                               const unsigned short* __restrict__ Bt,
                                               const float* __restrict__ res,
                                               float* __restrict__ cf,
                                               unsigned short* __restrict__ cb,
                                               int M, int N, int K) {
    __shared__ __align__(16) char sA[BM * BK * 2];
    __shared__ __align__(16) char sB[BN * BK * 2];
    int m0 = blockIdx.y * BM, n0 = blockIdx.x * BN;
    int tid = threadIdx.x;
    int lane = tid & 63, wave = tid >> 6;
    int wm = wave >> 1, wn = wave & 1;  // 2x2 waves, each does 64x64
    f32x4 acc[4][4] = {};

    for (int k0 = 0; k0 < K; k0 += BK) {
#pragma unroll
        for (int i = 0; i < 2; ++i) {
            int c = wave * 2 + i;                 // chunk 0..7, 1KB each (16 rows of 64B)
            int row = c * 16 + (lane >> 2);
            int col = (lane & 3) * 8;             // bf16 elements
            gload16(A  + ((size_t)(m0 + row) * K + k0 + col), (char*)sA + c * 1024);
            gload16(Bt + ((size_t)(n0 + row) * K + k0 + col), (char*)sB + c * 1024);
        }
        __syncthreads();
        bf16x8 af[4], bfr[4];
#pragma unroll
        for (int mi = 0; mi < 4; ++mi) {
            int ar = wm * 64 + mi * 16 + (lane & 15);
            af[mi] = *(const bf16x8*)(sA + ar * 64 + (lane >> 4) * 16);
        }
#pragma unroll
        for (int ni = 0; ni < 4; ++ni) {
            int br = wn * 64 + ni * 16 + (lane & 15);
            bfr[ni] = *(const bf16x8*)(sB + br * 64 + (lane >> 4) * 16);
        }
#pragma unroll
        for (int mi = 0; mi < 4; ++mi)
#pragma unroll
            for (int ni = 0; ni < 4; ++ni)
                acc[mi][ni] = __builtin_amdgcn_mfma_f32_16x16x32_bf16(af[mi], bfr[ni], acc[mi][ni], 0, 0, 0);
        __syncthreads();
    }

    int mbase = m0 + wm * 64 + (lane >> 4) * 4;
    int nbase = n0 + wn * 64 + (lane & 15);
#pragma unroll
    for (int mi = 0; mi < 4; ++mi)
#pragma unroll
        for (int ni = 0; ni < 4; ++ni)
#pragma unroll
            for (int r = 0; r < 4; ++r) {
                int m = mbase + mi * 16 + r;
                int n = nbase + ni * 16;
                float v = acc[mi][ni][r];
                if (EP == 1) v += res[(size_t)m * N + n];
                if (EP == 2) cb[(size_t)m * N + n] = f2bf(v);
                else         cf[(size_t)m * N + n] = v;
            }
}

// ---------------- beta = sigmoid(x @ Wb), Wb fp32 [D][16] ----------------
__global__ __launch_bounds__(256) void beta_kernel(const unsigned short* __restrict__ xb,
                                                   const float* __restrict__ Wb,
                                                   float* __restrict__ beta) {
    int row = blockIdx.x, tid = threadIdx.x;
    __shared__ float xs[DD];
    ushort4 xv = ((const ushort4*)(xb + (size_t)row * DD))[tid];
    xs[tid * 4 + 0] = bf2f(xv.x);
    xs[tid * 4 + 1] = bf2f(xv.y);
    xs[tid * 4 + 2] = bf2f(xv.z);
    xs[tid * 4 + 3] = bf2f(xv.w);
    __syncthreads();
    int hh = tid >> 4, j = tid & 15;
    float p = 0.f;
    const float* wp = Wb + hh;
#pragma unroll 8
    for (int d = j * 64; d < j * 64 + 64; ++d) p = fmaf(xs[d], wp[(size_t)d * HH], p);
    p += __shfl_xor(p, 1, 64);
    p += __shfl_xor(p, 2, 64);
    p += __shfl_xor(p, 4, 64);
    p += __shfl_xor(p, 8, 64);
    if (j == 0) beta[(size_t)row * HH + hh] = sigmoidf_(p);
}

// ---------------- silu + per-head l2norm (dk=64), in-place fp32 ----------------
__global__ __launch_bounds__(256) void silu_l2norm_kernel(float* __restrict__ x) {
    int row = blockIdx.x, tid = threadIdx.x;
    float4* p = (float4*)(x + (size_t)row * DD);
    float4 xv = p[tid];
    float s0 = siluf_(xv.x), s1 = siluf_(xv.y), s2 = siluf_(xv.z), s3 = siluf_(xv.w);
    float ss = s0 * s0 + s1 * s1 + s2 * s2 + s3 * s3;
    // head = 16 consecutive threads (64 elems)
    ss += __shfl_xor(ss, 1, 64);
    ss += __shfl_xor(ss, 2, 64);
    ss += __shfl_xor(ss, 4, 64);
    ss += __shfl_xor(ss, 8, 64);
    float sc = rsqrtf(ss + 1e-6f);
    p[tid] = make_float4(s0 * sc, s1 * sc, s2 * sc, s3 * sc);
}

// ---------------- silu in-place fp32 (grid-stride, float4) ----------------
__global__ void silu_kernel(float* __restrict__ x, int n4) {
    int i = blockIdx.x * blockDim.x + threadIdx.x;
    int stride = gridDim.x * blockDim.x;
    float4* p = (float4*)x;
    for (; i < n4; i += stride) {
        float4 v = p[i];
        v.x = siluf_(v.x); v.y = siluf_(v.y); v.z = siluf_(v.z); v.w = siluf_(v.w);
        p[i] = v;
    }
}

// ---------------- fp32 -> bf16 convert (grid-stride) ----------------
__global__ void cvt_f2b_kernel(const float* __restrict__ src, unsigned short* __restrict__ dst, int n4) {
    int i = blockIdx.x * blockDim.x + threadIdx.x;
    int stride = gridDim.x * blockDim.x;
    const float4* s = (const float4*)src;
    ushort4* d = (ushort4*)dst;
    for (; i < n4; i += stride) {
        float4 v = s[i];
        ushort4 o;
        o.x = f2bf(v.x); o.y = f2bf(v.y); o.z = f2bf(v.z); o.w = f2bf(v.w);
        d[i] = o;
    }
}

// ---------------- act = silu(g) * u, bf16 in-place on g ----------------
__global__ void silu_mul_kernel(unsigned short* __restrict__ g, const unsigned short* __restrict__ u, int n4) {
    int i = blockIdx.x * blockDim.x + threadIdx.x;
    int stride = gridDim.x * blockDim.x;
    ushort4* gp = (ushort4*)g;
    const ushort4* up = (const ushort4*)u;
    for (; i < n4; i += stride) {
        ushort4 gv = gp[i];
        ushort4 uv = up[i];
        ushort4 o;
        o.x = f2bf(siluf_(bf2f(gv.x)) * bf2f(uv.x));
        o.y = f2bf(siluf_(bf2f(gv.y)) * bf2f(uv.y));
        o.z = f2bf(siluf_(bf2f(gv.z)) * bf2f(uv.z));
        o.w = f2bf(siluf_(bf2f(gv.w)) * bf2f(uv.w));
        gp[i] = o;
    }
}

// ---------------- delta-rule sequential scan ----------------
// One block per (b,h). State A^T[v][k] (64x64 fp32) in registers:
// thread t owns A[v = t>>2][16*(t&3) .. +16). LDS double-slot staging + reg prefetch.
__global__ __launch_bounds__(256) void delta_kernel(const float* __restrict__ q,
                                                    const float* __restrict__ k,
                                                    const float* __restrict__ v,
                                                    const float* __restrict__ beta,
                                                    float* __restrict__ o) {
    int bh = blockIdx.x;
    int b = bh >> 4, h = bh & 15;
    int tid = threadIdx.x;
    __shared__ float lds[2][200]; // [0..64) k, [64..128) q, [128..192) v, [192] beta

    int rl = tid & 63;
    float r = 0.f;
    {
        size_t base = ((size_t)b * SS) * DD + (size_t)h * DKk;
        if (tid < 64) r = k[base + rl];
        else if (tid < 128) r = q[base + rl];
        else if (tid < 192) r = v[base + rl];
        else if (tid == 192) r = beta[((size_t)b * SS) * HH + h];
    }

    float a[16];
#pragma unroll
    for (int j = 0; j < 16; ++j) a[j] = 0.f;
    int vrow = tid >> 2, g = tid & 3;

    for (int t = 0; t < SS; ++t) {
        int slot = t & 1;
        if (tid <= 192) lds[slot][tid] = r;
        if (t + 1 < SS) {  // prefetch next step into regs (hidden under compute)
            size_t base = ((size_t)(b * SS + t + 1)) * DD + (size_t)h * DKk;
            if (tid < 64) r = k[base + rl];
            else if (tid < 128) r = q[base + rl];
            else if (tid < 192) r = v[base + rl];
            else if (tid == 192) r = beta[((size_t)(b * SS + t + 1)) * HH + h];
        }
        __syncthreads();
        const float* L = lds[slot];
        float kk[16];
#pragma unroll
        for (int j = 0; j < 16; ++j) kk[j] = L[g * 16 + j];
        float p = 0.f;
#pragma unroll
        for (int j = 0; j < 16; ++j) p = fmaf(a[j], kk[j], p);
        p += __shfl_xor(p, 1, 64);
        p += __shfl_xor(p, 2, 64);          // Sk[vrow] in all 4 lanes of the group
        float vv = L[128 + vrow];
        float bet = L[192];
        float tmp = bet * (vv - p);
        float op = 0.f;
#pragma unroll
        for (int j = 0; j < 16; ++j) {
            float qq = L[64 + g * 16 + j];
            a[j] = fmaf(tmp, kk[j], a[j]);  // state update
            op = fmaf(a[j], qq, op);        // o = A_new * q
        }
        op += __shfl_xor(op, 1, 64);
        op += __shfl_xor(op, 2, 64);
        if (g == 0) o[((size_t)(b * SS + t)) * DD + (size_t)h * DKk + vrow] = op;
    }
}

// ---------------- launch ----------------
extern "C" void kernel_launch(void* const* d_in, const int* in_sizes, int n_in,
                              void* d_out, int out_size, void* d_ws, size_t ws_size,
                              hipStream_t stream) {
    const float* hidden = (const float*)d_in[0];
    const float* Wq  = (const float*)d_in[1];
    const float* Wk  = (const float*)d_in[2];
    const float* Wv  = (const float*)d_in[3];
    const float* Wb  = (const float*)d_in[4];
    const float* Wo  = (const float*)d_in[5];
    const float* ln1 = (const float*)d_in[6];
    const float* ln2 = (const float*)d_in[7];
    const float* Wg  = (const float*)d_in[8];
    const float* Wu  = (const float*)d_in[9];
    const float* Wd  = (const float*)d_in[10];
    float* out = (float*)d_out;
    char* ws = (char*)d_ws;

    const size_t MB = 1024 * 1024;
    unsigned short* wq_t = (unsigned short*)(ws + 0 * MB);   // 2MB each
    unsigned short* wk_t = (unsigned short*)(ws + 2 * MB);
    unsigned short* wv_t = (unsigned short*)(ws + 4 * MB);
    unsigned short* wo_t = (unsigned short*)(ws + 6 * MB);
    unsigned short* wg_t = (unsigned short*)(ws + 8 * MB);   // 8MB
    unsigned short* wu_t = (unsigned short*)(ws + 16 * MB);  // 8MB
    unsigned short* wd_t = (unsigned short*)(ws + 24 * MB);  // 8MB
    float* hbuf          = (float*)(ws + 32 * MB);           // 16MB
    unsigned short* yb   = (unsigned short*)(ws + 48 * MB);  // 8MB
    float* qraw          = (float*)(ws + 56 * MB);           // 16MB
    float* kraw          = (float*)(ws + 72 * MB);           // 16MB
    float* vraw          = (float*)(ws + 88 * MB);           // 16MB
    float* betab         = (float*)(ws + 104 * MB);          // 0.25MB
    unsigned short* xb   = (unsigned short*)(ws + 104 * MB + 262144);  // 8MB
    float* obuf          = (float*)(ws + 112 * MB + 262144); // 16MB
    unsigned short* ob   = (unsigned short*)(ws + 128 * MB + 262144);  // 8MB -> 136.25MB total
    // aliases (dead-region reuse after the scan):
    unsigned short* gb = (unsigned short*)(ws + 56 * MB);    // 32MB over qraw+kraw
    unsigned short* ub = (unsigned short*)(ws + 88 * MB);    // 32MB over vraw+beta+xb+obuf(part)

    dim3 blk(256);

    // weights: fp32 [K][N] -> bf16 [N][K]
    transpose_cvt<<<dim3(DD / 32, DD / 32), blk, 0, stream>>>(Wq, wq_t, DD, DD);
    transpose_cvt<<<dim3(DD / 32, DD / 32), blk, 0, stream>>>(Wk, wk_t, DD, DD);
    transpose_cvt<<<dim3(DD / 32, DD / 32), blk, 0, stream>>>(Wv, wv_t, DD, DD);
    transpose_cvt<<<dim3(DD / 32, DD / 32), blk, 0, stream>>>(Wo, wo_t, DD, DD);
    transpose_cvt<<<dim3(FF / 32, DD / 32), blk, 0, stream>>>(Wg, wg_t, DD, FF);
    transpose_cvt<<<dim3(FF / 32, DD / 32), blk, 0, stream>>>(Wu, wu_t, DD, FF);
    transpose_cvt<<<dim3(DD / 32, FF / 32), blk, 0, stream>>>(Wd, wd_t, FF, DD);

    rmsnorm_bf16_kernel<<<ROWS, blk, 0, stream>>>(hidden, ln1, xb);

    gemm_bt<0><<<dim3(DD / BN, ROWS / BM), blk, 0, stream>>>(xb, wq_t, nullptr, qraw, nullptr, ROWS, DD, DD);
    gemm_bt<0><<<dim3(DD / BN, ROWS / BM), blk, 0, stream>>>(xb, wk_t, nullptr, kraw, nullptr, ROWS, DD, DD);
    gemm_bt<0><<<dim3(DD / BN, ROWS / BM), blk, 0, stream>>>(xb, wv_t, nullptr, vraw, nullptr, ROWS, DD, DD);
    beta_kernel<<<ROWS, blk, 0, stream>>>(xb, Wb, betab);

    silu_l2norm_kernel<<<ROWS, blk, 0, stream>>>(qraw);
    silu_l2norm_kernel<<<ROWS, blk, 0, stream>>>(kraw);
    silu_kernel<<<2048, blk, 0, stream>>>(vraw, ROWS * DD / 4);

    delta_kernel<<<BB * HH, blk, 0, stream>>>(qraw, kraw, vraw, betab, obuf);

    cvt_f2b_kernel<<<2048, blk, 0, stream>>>(obuf, ob, ROWS * DD / 4);
    gemm_bt<1><<<dim3(DD / BN, ROWS / BM), blk, 0, stream>>>(ob, wo_t, hidden, hbuf, nullptr, ROWS, DD, DD);

    rmsnorm_bf16_kernel<<<ROWS, blk, 0, stream>>>(hbuf, ln2, yb);

    gemm_bt<2><<<dim3(FF / BN, ROWS / BM), blk, 0, stream>>>(yb, wg_t, nullptr, nullptr, gb, ROWS, FF, DD);
    gemm_bt<2><<<dim3(FF / BN, ROWS / BM), blk, 0, stream>>>(yb, wu_t, nullptr, nullptr, ub, ROWS, FF, DD);

    silu_mul_kernel<<<4096, blk, 0, stream>>>(gb, ub, ROWS * FF / 4);

    gemm_bt<1><<<dim3(DD / BN, ROWS / BM), blk, 0, stream>>>(gb, wd_t, hbuf, out, nullptr, ROWS, DD, FF);
}

// Round 2
// 695.000 us; speedup vs baseline: 2.8771x; 2.8771x over previous
//
#include <hip/hip_runtime.h>
#include <hip/hip_bf16.h>
#include <stdint.h>

// Problem constants (B,S,D,F,H fixed by the reference)
#define BB 2
#define SS 2048
#define DD 1024
#define FF 4096
#define HH 16
#define ROWS (BB*SS)   // 4096
#define NC 32          // chunks per (b,h)  (2048/64)

typedef float f32x4 __attribute__((ext_vector_type(4)));
typedef __bf16 bf16x8 __attribute__((ext_vector_type(8)));

typedef __attribute__((address_space(1))) const void* gas1p;
typedef __attribute__((address_space(3))) void* las3p;

__device__ __forceinline__ void gload16(const void* g, void* l) {
    // wave-uniform LDS base; HW scatters lane i at base + i*16; global addr is per-lane
    __builtin_amdgcn_global_load_lds((gas1p)g, (las3p)l, 16, 0, 0);
}

__device__ __forceinline__ unsigned short f2bf(float f) {
    unsigned int u = __builtin_bit_cast(unsigned int, f);
    u += 0x7fffu + ((u >> 16) & 1u);   // round-to-nearest-even
    return (unsigned short)(u >> 16);
}
__device__ __forceinline__ float bf2f(unsigned short s) {
    unsigned int u = ((unsigned int)s) << 16;
    return __builtin_bit_cast(float, u);
}
__device__ __forceinline__ float sigmoidf_(float x) { return 1.f / (1.f + __expf(-x)); }
__device__ __forceinline__ float siluf_(float x)    { return x / (1.f + __expf(-x)); }

// XOR swizzle for 64x64 bf16 (128B-row) LDS tiles: spreads the 16-way bank conflict
__device__ __forceinline__ int swz(int b) { return b ^ (((b >> 7) & 7) << 4); }

// ---------------- transpose + fp32->bf16 convert: W[K][N] -> Wt[N][K] ----------------
__global__ __launch_bounds__(256) void transpose_cvt(const float* __restrict__ W,
                                                     unsigned short* __restrict__ Wt,
                                                     int K, int N) {
    __shared__ float tile[32][33];
    int tx = threadIdx.x & 31, ty = threadIdx.x >> 5; // ty 0..7
    int n0 = blockIdx.x * 32, k0 = blockIdx.y * 32;
#pragma unroll
    for (int i = 0; i < 4; ++i)
        tile[ty + 8 * i][tx] = W[(size_t)(k0 + ty + 8 * i) * N + n0 + tx];
    __syncthreads();
#pragma unroll
    for (int i = 0; i < 4; ++i)
        Wt[(size_t)(n0 + ty + 8 * i) * K + k0 + tx] = f2bf(tile[tx][ty + 8 * i]);
}

// ---------------- RMSNorm (D=1024) -> bf16 ----------------
__global__ __launch_bounds__(256) void rmsnorm_bf16_kernel(const float* __restrict__ src,
                                                           const float* __restrict__ w,
                                                           unsigned short* __restrict__ dst) {
    int row = blockIdx.x;
    int tid = threadIdx.x;
    float4 x = ((const float4*)(src + (size_t)row * DD))[tid];
    float ss = x.x * x.x + x.y * x.y + x.z * x.z + x.w * x.w;
#pragma unroll
    for (int m = 1; m < 64; m <<= 1) ss += __shfl_xor(ss, m, 64);
    __shared__ float ws4[4];
    if ((tid & 63) == 0) ws4[tid >> 6] = ss;
    __syncthreads();
    ss = ws4[0] + ws4[1] + ws4[2] + ws4[3];
    float sc = rsqrtf(ss * (1.f / DD) + 1e-6f);
    float4 wv = ((const float4*)w)[tid];
    ushort4 o;
    o.x = f2bf(x.x * sc * wv.x);
    o.y = f2bf(x.y * sc * wv.y);
    o.z = f2bf(x.z * sc * wv.z);
    o.w = f2bf(x.w * sc * wv.w);
    ((ushort4*)(dst + (size_t)row * DD))[tid] = o;
}

// ---------------- bf16 GEMM: C[M][N] = A[M][K] * Bt[N][K]^T ----------------
// EP 0: fp32 out; EP 1: fp32 out + fp32 residual; EP 2: bf16 out
#define BM 128
#define BN 128
#define BK 32

template <int EP>
__global__ __launch_bounds__(256) void gemm_bt(const unsigned short* __restrict__ A,
                                               const unsigned short* __restrict__ Bt,
                                               const float* __restrict__ res,
                                               float* __restrict__ cf,
                                               unsigned short* __restrict__ cb,
                                               int M, int N, int K) {
    __shared__ __align__(16) char sA[BM * BK * 2];
    __shared__ __align__(16) char sB[BN * BK * 2];
    int m0 = blockIdx.y * BM, n0 = blockIdx.x * BN;
    int tid = threadIdx.x;
    int lane = tid & 63, wave = tid >> 6;
    int wm = wave >> 1, wn = wave & 1;  // 2x2 waves, each does 64x64
    f32x4 acc[4][4] = {};

    for (int k0 = 0; k0 < K; k0 += BK) {
#pragma unroll
        for (int i = 0; i < 2; ++i) {
            int c = wave * 2 + i;                 // chunk 0..7, 1KB each (16 rows of 64B)
            int row = c * 16 + (lane >> 2);
            int col = (lane & 3) * 8;             // bf16 elements
            gload16(A  + ((size_t)(m0 + row) * K + k0 + col), (char*)sA + c * 1024);
            gload16(Bt + ((size_t)(n0 + row) * K + k0 + col), (char*)sB + c * 1024);
        }
        __syncthreads();
        bf16x8 af[4], bfr[4];
#pragma unroll
        for (int mi = 0; mi < 4; ++mi) {
            int ar = wm * 64 + mi * 16 + (lane & 15);
            af[mi] = *(const bf16x8*)(sA + ar * 64 + (lane >> 4) * 16);
        }
#pragma unroll
        for (int ni = 0; ni < 4; ++ni) {
            int br = wn * 64 + ni * 16 + (lane & 15);
            bfr[ni] = *(const bf16x8*)(sB + br * 64 + (lane >> 4) * 16);
        }
#pragma unroll
        for (int mi = 0; mi < 4; ++mi)
#pragma unroll
            for (int ni = 0; ni < 4; ++ni)
                acc[mi][ni] = __builtin_amdgcn_mfma_f32_16x16x32_bf16(af[mi], bfr[ni], acc[mi][ni], 0, 0, 0);
        __syncthreads();
    }

    int mbase = m0 + wm * 64 + (lane >> 4) * 4;
    int nbase = n0 + wn * 64 + (lane & 15);
#pragma unroll
    for (int mi = 0; mi < 4; ++mi)
#pragma unroll
        for (int ni = 0; ni < 4; ++ni)
#pragma unroll
            for (int r = 0; r < 4; ++r) {
                int m = mbase + mi * 16 + r;
                int n = nbase + ni * 16;
                float v = acc[mi][ni][r];
                if (EP == 1) v += res[(size_t)m * N + n];
                if (EP == 2) cb[(size_t)m * N + n] = f2bf(v);
                else         cf[(size_t)m * N + n] = v;
            }
}

// ---------------- beta = sigmoid(x @ Wb), Wb fp32 [D][16] ----------------
__global__ __launch_bounds__(256) void beta_kernel(const unsigned short* __restrict__ xb,
                                                   const float* __restrict__ Wb,
                                                   float* __restrict__ beta) {
    int row = blockIdx.x, tid = threadIdx.x;
    __shared__ float xs[DD];
    ushort4 xv = ((const ushort4*)(xb + (size_t)row * DD))[tid];
    xs[tid * 4 + 0] = bf2f(xv.x);
    xs[tid * 4 + 1] = bf2f(xv.y);
    xs[tid * 4 + 2] = bf2f(xv.z);
    xs[tid * 4 + 3] = bf2f(xv.w);
    __syncthreads();
    int hh = tid >> 4, j = tid & 15;
    float p = 0.f;
    const float* wp = Wb + hh;
#pragma unroll 8
    for (int d = j * 64; d < j * 64 + 64; ++d) p = fmaf(xs[d], wp[(size_t)d * HH], p);
    p += __shfl_xor(p, 1, 64);
    p += __shfl_xor(p, 2, 64);
    p += __shfl_xor(p, 4, 64);
    p += __shfl_xor(p, 8, 64);
    if (j == 0) beta[(size_t)row * HH + hh] = sigmoidf_(p);
}

// ---------------- act = silu(g) * u, bf16 in-place on g ----------------
__global__ void silu_mul_kernel(unsigned short* __restrict__ g, const unsigned short* __restrict__ u, int n4) {
    int i = blockIdx.x * blockDim.x + threadIdx.x;
    int stride = gridDim.x * blockDim.x;
    ushort4* gp = (ushort4*)g;
    const ushort4* up = (const ushort4*)u;
    for (; i < n4; i += stride) {
        ushort4 gv = gp[i];
        ushort4 uv = up[i];
        ushort4 o;
        o.x = f2bf(siluf_(bf2f(gv.x)) * bf2f(uv.x));
        o.y = f2bf(siluf_(bf2f(gv.y)) * bf2f(uv.y));
        o.z = f2bf(siluf_(bf2f(gv.z)) * bf2f(uv.z));
        o.w = f2bf(siluf_(bf2f(gv.w)) * bf2f(uv.w));
        gp[i] = o;
    }
}

// ================= chunked delta rule =================
// Per-chunk matrices are 64x64. MFMA op(X,Y)[m][n] = sum_k X[m][k]*Y[n][k]
// (both operands read row-major, [idx][k], idx = lane&15).
// D-layout: n = lane&15, m = 16*tile_m + (lane>>4)*4 + r.

__device__ __forceinline__ bf16x8 ldsfrag(const char* mat, int row, int kt, int lane) {
    return *(const bf16x8*)(mat + swz(row * 128 + kt * 64 + (lane >> 4) * 16));
}

// generic 64x64x64 matmul on swizzled LDS bf16 matrices; wave w owns m-rows [16w,16w+16)
template <bool INIT_P>
__device__ __forceinline__ void mm64(const char* X, const char* Y, const char* P,
                                     f32x4 acc[4], int w, int lane) {
    int g = lane >> 4;
#pragma unroll
    for (int j = 0; j < 4; ++j) {
        if (INIT_P) {
#pragma unroll
            for (int r = 0; r < 4; ++r) {
                int m = 16 * w + g * 4 + r, n = (lane & 15) + 16 * j;
                acc[j][r] = bf2f(*(const unsigned short*)(P + swz(m * 128 + n * 2)));
            }
        } else {
            acc[j] = (f32x4){0.f, 0.f, 0.f, 0.f};
        }
    }
    bf16x8 xs0 = ldsfrag(X, 16 * w + (lane & 15), 0, lane);
    bf16x8 xs1 = ldsfrag(X, 16 * w + (lane & 15), 1, lane);
#pragma unroll
    for (int j = 0; j < 4; ++j) {
        bf16x8 y0 = ldsfrag(Y, 16 * j + (lane & 15), 0, lane);
        bf16x8 y1 = ldsfrag(Y, 16 * j + (lane & 15), 1, lane);
        acc[j] = __builtin_amdgcn_mfma_f32_16x16x32_bf16(xs0, y0, acc[j], 0, 0, 0);
        acc[j] = __builtin_amdgcn_mfma_f32_16x16x32_bf16(xs1, y1, acc[j], 0, 0, 0);
    }
}

// row-major LDS write. mode: 0 plain, 1 strict-lower (keep n<m), 2 P1 = I - strict(L)
__device__ __forceinline__ void wR(char* D, const f32x4 acc[4], int w, int lane, int mode) {
    int g = lane >> 4;
#pragma unroll
    for (int j = 0; j < 4; ++j)
#pragma unroll
        for (int r = 0; r < 4; ++r) {
            int m = 16 * w + g * 4 + r, n = (lane & 15) + 16 * j;
            float v = acc[j][r];
            if (mode >= 1) v = (n < m) ? v : 0.f;
            if (mode == 2) v = ((m == n) ? 1.f : 0.f) - v;
            *(unsigned short*)(D + swz(m * 128 + n * 2)) = f2bf(v);
        }
}

// transposed packed LDS write: D[n][m0..m0+3]. mode: 0 plain, 1 strict (keep n<m)
__device__ __forceinline__ void wT(char* D, const f32x4 acc[4], int w, int lane, int mode) {
    int g = lane >> 4;
#pragma unroll
    for (int j = 0; j < 4; ++j) {
        int n = (lane & 15) + 16 * j, m0 = 16 * w + g * 4;
        ushort4 pk;
        pk.x = (mode == 1 && !(n < m0 + 0)) ? (unsigned short)0 : f2bf(acc[j][0]);
        pk.y = (mode == 1 && !(n < m0 + 1)) ? (unsigned short)0 : f2bf(acc[j][1]);
        pk.z = (mode == 1 && !(n < m0 + 2)) ? (unsigned short)0 : f2bf(acc[j][2]);
        pk.w = (mode == 1 && !(n < m0 + 3)) ? (unsigned short)0 : f2bf(acc[j][3]);
        *(ushort4*)(D + swz(n * 128 + m0 * 2)) = pk;
    }
}

__device__ __forceinline__ void load16bf(const unsigned short* p, float* v) {
    uint4 a = *(const uint4*)p, b = *(const uint4*)(p + 8);
    unsigned int u0[8] = {a.x, a.y, a.z, a.w, b.x, b.y, b.z, b.w};
#pragma unroll
    for (int i = 0; i < 8; ++i) {
        v[2 * i]     = bf2f((unsigned short)(u0[i] & 0xffffu));
        v[2 * i + 1] = bf2f((unsigned short)(u0[i] >> 16));
    }
}

// -------- parallel per-chunk prep: silu/l2norm/beta-scale + T=(I+L)^-1 + outputs --------
// grid: 1024 blocks = (b,h,c); 256 threads. Outputs per chunk (40KB):
//   Q[t][dk] bf16 | KT[dk][t] bf16 | A[t][s] bf16 (incl-tril QK^T) | W[t][dk]=T*K_b | U0T[dv][t]=(T*V_b)^T
__global__ __launch_bounds__(256) void delta_prep_kernel(const unsigned short* __restrict__ qb,
                                                         const unsigned short* __restrict__ kb,
                                                         const unsigned short* __restrict__ vb,
                                                         const float* __restrict__ betab,
                                                         char* __restrict__ chunkbuf) {
    __shared__ __align__(16) char sK[8192], sKb[8192], sKbT[8192], sVbT[8192], sQ[8192];
    __shared__ __align__(16) char mA[8192], mAT[8192], mB2[8192], mBT[8192], mP0[8192], mP1[8192];

    int ci = blockIdx.x;
    int c = ci & 31, h = (ci >> 5) & 15, b = ci >> 9;
    int tid = threadIdx.x;
    int lane = tid & 63, w = tid >> 6;

    char* cbuf = chunkbuf + (size_t)ci * 40960;
    unsigned short* Qg  = (unsigned short*)(cbuf);
    unsigned short* KTg = (unsigned short*)(cbuf + 8192);
    unsigned short* Ag  = (unsigned short*)(cbuf + 16384);
    unsigned short* Wg  = (unsigned short*)(cbuf + 24576);
    unsigned short* U0g = (unsigned short*)(cbuf + 32768);

    // ---- staging: 4 threads per row, 16 elems each ----
    {
        int trow = tid >> 2, part = tid & 3, d0 = part * 16;
        size_t rg = (size_t)b * SS + c * 64 + trow;
        float bet = betab[rg * HH + h];
        size_t base = rg * DD + h * 64 + d0;

        float qv[16], kv[16], vv[16];
        load16bf(qb + base, qv);
        load16bf(kb + base, kv);
        load16bf(vb + base, vv);

        float ssq = 0.f, ssk = 0.f;
#pragma unroll
        for (int i = 0; i < 16; ++i) {
            qv[i] = siluf_(qv[i]); ssq += qv[i] * qv[i];
            kv[i] = siluf_(kv[i]); ssk += kv[i] * kv[i];
            vv[i] = siluf_(vv[i]);
        }
        ssq += __shfl_xor(ssq, 1, 64); ssq += __shfl_xor(ssq, 2, 64);
        ssk += __shfl_xor(ssk, 1, 64); ssk += __shfl_xor(ssk, 2, 64);
        float scq = rsqrtf(ssq + 1e-6f), sck = rsqrtf(ssk + 1e-6f);
#pragma unroll
        for (int i = 0; i < 16; ++i) { qv[i] *= scq; kv[i] *= sck; }

        // packed swizzled LDS writes (4x ushort4 per matrix) + global Q
#pragma unroll
        for (int m = 0; m < 4; ++m) {
            ushort4 pq, pk_, pkb;
#pragma unroll
            for (int r = 0; r < 4; ++r) {
                ((unsigned short*)&pq)[r]  = f2bf(qv[4 * m + r]);
                ((unsigned short*)&pk_)[r] = f2bf(kv[4 * m + r]);
                ((unsigned short*)&pkb)[r] = f2bf(bet * kv[4 * m + r]);
            }
            int bo = trow * 128 + (d0 + 4 * m) * 2;
            *(ushort4*)(sQ + swz(bo))  = pq;
            *(ushort4*)(sK + swz(bo))  = pk_;
            *(ushort4*)(sKb + swz(bo)) = pkb;
            *(ushort4*)(Qg + trow * 64 + d0 + 4 * m) = pq;
        }
        // scalar transposed writes: KbT, VbT (LDS), KT (global)
#pragma unroll
        for (int e = 0; e < 16; ++e) {
            int d = d0 + e;
            *(unsigned short*)(sKbT + swz(d * 128 + trow * 2)) = f2bf(bet * kv[e]);
            *(unsigned short*)(sVbT + swz(d * 128 + trow * 2)) = f2bf(bet * vv[e]);
            KTg[d * 64 + trow] = f2bf(kv[e]);
        }
    }
    __syncthreads();

    f32x4 acc[4];
    // L = strict_tril(K_b K^T); P1 = I - L
    mm64<false>(sKb, sK, nullptr, acc, w, lane);
    wR(mA, acc, w, lane, 1);   // L
    wT(mAT, acc, w, lane, 1);  // L^T
    wR(mP0, acc, w, lane, 2);  // P1
    __syncthreads();

    // T = (I-L)(I+L^2)(I+L^4)(I+L^8)(I+L^16)(I+L^32)
    char *cX = mA, *cXT = mAT, *nX = mB2, *nXT = mBT, *pc = mP0, *pn = mP1;
#pragma unroll
    for (int s = 0; s < 5; ++s) {
        mm64<false>(cX, cXT, nullptr, acc, w, lane);   // next power = cur^2
        wR(nX, acc, w, lane, 0);
        wT(nXT, acc, w, lane, 0);
        __syncthreads();
        mm64<true>(pc, nXT, pc, acc, w, lane);         // P = P + P * power
        wR(pn, acc, w, lane, 0);
        __syncthreads();
        char* t;
        t = cX; cX = nX; nX = t;
        t = cXT; cXT = nXT; nXT = t;
        t = pc; pc = pn; pn = t;
    }
    // pc now holds T

    int g = lane >> 4;
    // A = incl_tril(Q K^T): R = op(K, Q) -> write transposed packed to global, keep s<=t
    mm64<false>(sK, sQ, nullptr, acc, w, lane);
#pragma unroll
    for (int j = 0; j < 4; ++j) {
        int n = (lane & 15) + 16 * j, m0 = 16 * w + g * 4;  // n=t, m=s
        ushort4 pk;
        pk.x = (m0 + 0 <= n) ? f2bf(acc[j][0]) : (unsigned short)0;
        pk.y = (m0 + 1 <= n) ? f2bf(acc[j][1]) : (unsigned short)0;
        pk.z = (m0 + 2 <= n) ? f2bf(acc[j][2]) : (unsigned short)0;
        pk.w = (m0 + 3 <= n) ? f2bf(acc[j][3]) : (unsigned short)0;
        *(ushort4*)(Ag + n * 64 + m0) = pk;
    }
    // W = T*K_b: R = op(KbT, T) gives W^T -> transposed write = W[t][dk]
    mm64<false>(sKbT, pc, nullptr, acc, w, lane);
#pragma unroll
    for (int j = 0; j < 4; ++j) {
        int n = (lane & 15) + 16 * j, m0 = 16 * w + g * 4;  // n=t, m=dk
        ushort4 pk;
        pk.x = f2bf(acc[j][0]); pk.y = f2bf(acc[j][1]);
        pk.z = f2bf(acc[j][2]); pk.w = f2bf(acc[j][3]);
        *(ushort4*)(Wg + n * 64 + m0) = pk;
    }
    // U0 = T*V_b: R = op(T, VbT) = U0[t][dv] -> transposed write = U0T[dv][t]
    mm64<false>(pc, sVbT, nullptr, acc, w, lane);
#pragma unroll
    for (int j = 0; j < 4; ++j) {
        int n = (lane & 15) + 16 * j, m0 = 16 * w + g * 4;  // n=dv, m=t
        ushort4 pk;
        pk.x = f2bf(acc[j][0]); pk.y = f2bf(acc[j][1]);
        pk.z = f2bf(acc[j][2]); pk.w = f2bf(acc[j][3]);
        *(ushort4*)(U0g + n * 64 + m0) = pk;
    }
}

// -------- sequential inter-chunk scan: 32 blocks = (b,h), 256 threads --------
// State S^T[dv][dk] in fp32 accs (wave w owns dv rows [16w,16w+16)) + bf16 LDS mirror.
// Per chunk: U^T = U0T - op(Sl,W); oT = op(Sl,Q) + op(UT,A); S^T += op(UT,KT).
__global__ __launch_bounds__(256) void delta_seq_kernel(const char* __restrict__ chunkbuf,
                                                        unsigned short* __restrict__ ob) {
    __shared__ __align__(16) char stg[2 * 40960 + 8192 + 8192];
    int bh = blockIdx.x;
    int b = bh >> 4, h = bh & 15;
    int tid = threadIdx.x;
    int lane = tid & 63, w = tid >> 6, g = lane >> 4;

    char* UTw = stg + 81920 + w * 2048;   // wave-private U^T slice [16][64] bf16 swz
    char* Slw = stg + 90112 + w * 2048;   // wave-private S^T slice [16][64] bf16 swz

    // zero S
    f32x4 s_acc[4];
#pragma unroll
    for (int j = 0; j < 4; ++j) s_acc[j] = (f32x4){0.f, 0.f, 0.f, 0.f};
    uint4 z4 = {0, 0, 0, 0};
    *(uint4*)(Slw + lane * 32) = z4;
    *(uint4*)(Slw + lane * 32 + 16) = z4;

    const char* cbase = chunkbuf + (size_t)bh * NC * 40960;
    int lo = (lane * 16) ^ ((lane >> 3) << 4);   // pre-swizzled source offset per lane
    int pw = 10 * w;

    // prologue: stage chunk 0 into buffer 0
    {
        const char* src = cbase;
        char* dst = stg;
#pragma unroll
        for (int p = 0; p < 10; ++p)
            gload16(src + (pw + p) * 1024 + lo, dst + (pw + p) * 1024);
    }

    for (int c = 0; c < NC; ++c) {
        // issue prefetch for next chunk (wraps harmlessly at c=31)
        {
            const char* src = cbase + (size_t)((c + 1) & 31) * 40960;
            char* dst = stg + ((c + 1) & 1) * 40960;
#pragma unroll
            for (int p = 0; p < 10; ++p)
                gload16(src + (pw + p) * 1024 + lo, dst + (pw + p) * 1024);
        }
        asm volatile("s_waitcnt vmcnt(10)" ::: "memory");
        __builtin_amdgcn_s_barrier();
        __builtin_amdgcn_sched_barrier(0);

        const char* cur = stg + (c & 1) * 40960;
        const char* Qm = cur, *KTm = cur + 8192, *Am = cur + 16384, *Wm = cur + 24576, *U0m = cur + 32768;

        // X-frags from wave-private S^T
        bf16x8 xs0 = ldsfrag(Slw, lane & 15, 0, lane);
        bf16x8 xs1 = ldsfrag(Slw, lane & 15, 1, lane);

        // M1: ut = op(Sl, W)   (to be subtracted from U0T)
        f32x4 ut[4];
        f32x4 oa[4];
#pragma unroll
        for (int j = 0; j < 4; ++j) { ut[j] = (f32x4){0.f, 0.f, 0.f, 0.f}; oa[j] = (f32x4){0.f, 0.f, 0.f, 0.f}; }
#pragma unroll
        for (int j = 0; j < 4; ++j) {
            bf16x8 y0 = ldsfrag(Wm, 16 * j + (lane & 15), 0, lane);
            bf16x8 y1 = ldsfrag(Wm, 16 * j + (lane & 15), 1, lane);
            ut[j] = __builtin_amdgcn_mfma_f32_16x16x32_bf16(xs0, y0, ut[j], 0, 0, 0);
            ut[j] = __builtin_amdgcn_mfma_f32_16x16x32_bf16(xs1, y1, ut[j], 0, 0, 0);
        }
        // M2a: oT = op(Sl, Q)
#pragma unroll
        for (int j = 0; j < 4; ++j) {
            bf16x8 y0 = ldsfrag(Qm, 16 * j + (lane & 15), 0, lane);
            bf16x8 y1 = ldsfrag(Qm, 16 * j + (lane & 15), 1, lane);
            oa[j] = __builtin_amdgcn_mfma_f32_16x16x32_bf16(xs0, y0, oa[j], 0, 0, 0);
            oa[j] = __builtin_amdgcn_mfma_f32_16x16x32_bf16(xs1, y1, oa[j], 0, 0, 0);
        }
        // finalize U^T = U0T - ut, write to wave-private LDS (bf16, swz)
#pragma unroll
        for (int j = 0; j < 4; ++j)
#pragma unroll
            for (int r = 0; r < 4; ++r) {
                int m = 16 * w + g * 4 + r;          // dv (global row in U0T)
                int n = (lane & 15) + 16 * j;        // t
                float u0 = bf2f(*(const unsigned short*)(U0m + swz(m * 128 + n * 2)));
                float u = u0 - ut[j][r];
                *(unsigned short*)(UTw + swz((g * 4 + r) * 128 + n * 2)) = f2bf(u);
            }
        // M2b + M3 (UT wave-private: no barrier needed; compiler orders ds ops)
        bf16x8 us0 = ldsfrag(UTw, lane & 15, 0, lane);
        bf16x8 us1 = ldsfrag(UTw, lane & 15, 1, lane);
#pragma unroll
        for (int j = 0; j < 4; ++j) {
            bf16x8 y0 = ldsfrag(Am, 16 * j + (lane & 15), 0, lane);
            bf16x8 y1 = ldsfrag(Am, 16 * j + (lane & 15), 1, lane);
            oa[j] = __builtin_amdgcn_mfma_f32_16x16x32_bf16(us0, y0, oa[j], 0, 0, 0);
            oa[j] = __builtin_amdgcn_mfma_f32_16x16x32_bf16(us1, y1, oa[j], 0, 0, 0);
        }
#pragma unroll
        for (int j = 0; j < 4; ++j) {
            bf16x8 y0 = ldsfrag(KTm, 16 * j + (lane & 15), 0, lane);
            bf16x8 y1 = ldsfrag(KTm, 16 * j + (lane & 15), 1, lane);
            s_acc[j] = __builtin_amdgcn_mfma_f32_16x16x32_bf16(us0, y0, s_acc[j], 0, 0, 0);
            s_acc[j] = __builtin_amdgcn_mfma_f32_16x16x32_bf16(us1, y1, s_acc[j], 0, 0, 0);
        }
        // o store: oT[dv][t] -> transposed packed global o[t][h*64+dv..+3] bf16
#pragma unroll
        for (int j = 0; j < 4; ++j) {
            int n = (lane & 15) + 16 * j;            // t local
            size_t tg = (size_t)b * SS + c * 64 + n;
            int col = h * 64 + 16 * w + g * 4;
            ushort4 pk;
            pk.x = f2bf(oa[j][0]); pk.y = f2bf(oa[j][1]);
            pk.z = f2bf(oa[j][2]); pk.w = f2bf(oa[j][3]);
            *(ushort4*)(ob + tg * DD + col) = pk;
        }
        // refresh bf16 S mirror from fp32 accs (wave-private)
#pragma unroll
        for (int j = 0; j < 4; ++j)
#pragma unroll
            for (int r = 0; r < 4; ++r) {
                int n = (lane & 15) + 16 * j;        // dk
                *(unsigned short*)(Slw + swz((g * 4 + r) * 128 + n * 2)) = f2bf(s_acc[j][r]);
            }

        asm volatile("" ::: "memory");
        __builtin_amdgcn_s_barrier();   // all waves done reading cur before it is re-staged
        __builtin_amdgcn_sched_barrier(0);
    }
}

// ---------------- launch ----------------
extern "C" void kernel_launch(void* const* d_in, const int* in_sizes, int n_in,
                              void* d_out, int out_size, void* d_ws, size_t ws_size,
                              hipStream_t stream) {
    const float* hidden = (const float*)d_in[0];
    const float* Wq  = (const float*)d_in[1];
    const float* Wk  = (const float*)d_in[2];
    const float* Wv  = (const float*)d_in[3];
    const float* Wb  = (const float*)d_in[4];
    const float* Wo  = (const float*)d_in[5];
    const float* ln1 = (const float*)d_in[6];
    const float* ln2 = (const float*)d_in[7];
    const float* Wg  = (const float*)d_in[8];
    const float* Wu  = (const float*)d_in[9];
    const float* Wd  = (const float*)d_in[10];
    float* out = (float*)d_out;
    char* ws = (char*)d_ws;

    const size_t MB = 1024 * 1024;
    unsigned short* wq_t = (unsigned short*)(ws + 0 * MB);   // 2MB each
    unsigned short* wk_t = (unsigned short*)(ws + 2 * MB);
    unsigned short* wv_t = (unsigned short*)(ws + 4 * MB);
    unsigned short* wo_t = (unsigned short*)(ws + 6 * MB);
    unsigned short* wg_t = (unsigned short*)(ws + 8 * MB);   // 8MB
    unsigned short* wu_t = (unsigned short*)(ws + 16 * MB);  // 8MB
    unsigned short* wd_t = (unsigned short*)(ws + 24 * MB);  // 8MB
    float* hbuf          = (float*)(ws + 32 * MB);           // 16MB fp32
    unsigned short* yb   = (unsigned short*)(ws + 48 * MB);  // 8MB
    unsigned short* qb   = (unsigned short*)(ws + 56 * MB);  // 8MB bf16
    unsigned short* kb   = (unsigned short*)(ws + 64 * MB);  // 8MB
    unsigned short* vb   = (unsigned short*)(ws + 72 * MB);  // 8MB
    float* betab         = (float*)(ws + 80 * MB);           // 0.25MB
    unsigned short* xb   = (unsigned short*)(ws + 80 * MB + 262144);   // 8MB
    unsigned short* ob   = (unsigned short*)(ws + 88 * MB + 262144);   // 8MB
    char* chunkbuf       = ws + 96 * MB + 262144;            // 40MB -> total 136.25MB
    // aliases for MLP stage (dead regions after delta):
    unsigned short* gb = (unsigned short*)(ws + 56 * MB);    // 32MB over qb..betab+
    unsigned short* ub = (unsigned short*)(ws + 96 * MB + 262144);     // 32MB over chunkbuf

    dim3 blk(256);

    // weights: fp32 [K][N] -> bf16 [N][K]
    transpose_cvt<<<dim3(DD / 32, DD / 32), blk, 0, stream>>>(Wq, wq_t, DD, DD);
    transpose_cvt<<<dim3(DD / 32, DD / 32), blk, 0, stream>>>(Wk, wk_t, DD, DD);
    transpose_cvt<<<dim3(DD / 32, DD / 32), blk, 0, stream>>>(Wv, wv_t, DD, DD);
    transpose_cvt<<<dim3(DD / 32, DD / 32), blk, 0, stream>>>(Wo, wo_t, DD, DD);
    transpose_cvt<<<dim3(FF / 32, DD / 32), blk, 0, stream>>>(Wg, wg_t, DD, FF);
    transpose_cvt<<<dim3(FF / 32, DD / 32), blk, 0, stream>>>(Wu, wu_t, DD, FF);
    transpose_cvt<<<dim3(DD / 32, FF / 32), blk, 0, stream>>>(Wd, wd_t, FF, DD);

    rmsnorm_bf16_kernel<<<ROWS, blk, 0, stream>>>(hidden, ln1, xb);

    gemm_bt<2><<<dim3(DD / BN, ROWS / BM), blk, 0, stream>>>(xb, wq_t, nullptr, nullptr, qb, ROWS, DD, DD);
    gemm_bt<2><<<dim3(DD / BN, ROWS / BM), blk, 0, stream>>>(xb, wk_t, nullptr, nullptr, kb, ROWS, DD, DD);
    gemm_bt<2><<<dim3(DD / BN, ROWS / BM), blk, 0, stream>>>(xb, wv_t, nullptr, nullptr, vb, ROWS, DD, DD);
    beta_kernel<<<ROWS, blk, 0, stream>>>(xb, Wb, betab);

    delta_prep_kernel<<<1024, blk, 0, stream>>>(qb, kb, vb, betab, chunkbuf);
    delta_seq_kernel<<<BB * HH, blk, 0, stream>>>(chunkbuf, ob);

    gemm_bt<1><<<dim3(DD / BN, ROWS / BM), blk, 0, stream>>>(ob, wo_t, hidden, hbuf, nullptr, ROWS, DD, DD);

    rmsnorm_bf16_kernel<<<ROWS, blk, 0, stream>>>(hbuf, ln2, yb);

    gemm_bt<2><<<dim3(FF / BN, ROWS / BM), blk, 0, stream>>>(yb, wg_t, nullptr, nullptr, gb, ROWS, FF, DD);
    gemm_bt<2><<<dim3(FF / BN, ROWS / BM), blk, 0, stream>>>(yb, wu_t, nullptr, nullptr, ub, ROWS, FF, DD);

    silu_mul_kernel<<<4096, blk, 0, stream>>>(gb, ub, ROWS * FF / 4);

    gemm_bt<1><<<dim3(DD / BN, ROWS / BM), blk, 0, stream>>>(gb, wd_t, hbuf, out, nullptr, ROWS, DD, FF);
}

// Round 3
// 555.047 us; speedup vs baseline: 3.6025x; 1.2521x over previous
//
#include <hip/hip_runtime.h>
#include <hip/hip_bf16.h>
#include <stdint.h>

// Problem constants (B,S,D,F,H fixed by the reference)
#define BB 2
#define SS 2048
#define DD 1024
#define FF 4096
#define HH 16
#define ROWS (BB*SS)   // 4096
#define NC 32          // chunks per (b,h)  (2048/64)
#define NQKV 3200      // 3*1024 (q,k,v) + 16 (beta) padded to mult of 128

typedef float f32x4 __attribute__((ext_vector_type(4)));
typedef __bf16 bf16x8 __attribute__((ext_vector_type(8)));

typedef __attribute__((address_space(1))) const void* gas1p;
typedef __attribute__((address_space(3))) void* las3p;

__device__ __forceinline__ void gload16(const void* g, void* l) {
    // wave-uniform LDS base; HW scatters lane i at base + i*16; global addr is per-lane
    __builtin_amdgcn_global_load_lds((gas1p)g, (las3p)l, 16, 0, 0);
}

__device__ __forceinline__ unsigned short f2bf(float f) {
    unsigned int u = __builtin_bit_cast(unsigned int, f);
    u += 0x7fffu + ((u >> 16) & 1u);   // round-to-nearest-even
    return (unsigned short)(u >> 16);
}
__device__ __forceinline__ float bf2f(unsigned short s) {
    unsigned int u = ((unsigned int)s) << 16;
    return __builtin_bit_cast(float, u);
}
__device__ __forceinline__ float sigmoidf_(float x) { return 1.f / (1.f + __expf(-x)); }
__device__ __forceinline__ float siluf_(float x)    { return x / (1.f + __expf(-x)); }

// XOR swizzle for 64x64 bf16 (128B-row) LDS tiles: spreads the 16-way bank conflict
__device__ __forceinline__ int swz(int b) { return b ^ (((b >> 7) & 7) << 4); }

// ---------------- transpose + fp32->bf16 convert: W[K][N] -> Wt[N][K] ----------------
__device__ __forceinline__ void tp_body(const float* __restrict__ W,
                                        unsigned short* __restrict__ Wt,
                                        int K, int N, int bx, int by, int tid) {
    __shared__ float tile[32][33];
    int tx = tid & 31, ty = tid >> 5; // ty 0..7
    int n0 = bx * 32, k0 = by * 32;
#pragma unroll
    for (int i = 0; i < 4; ++i)
        tile[ty + 8 * i][tx] = W[(size_t)(k0 + ty + 8 * i) * N + n0 + tx];
    __syncthreads();
#pragma unroll
    for (int i = 0; i < 4; ++i)
        Wt[(size_t)(n0 + ty + 8 * i) * K + k0 + tx] = f2bf(tile[tx][ty + 8 * i]);
}

__global__ __launch_bounds__(256) void transpose_cvt(const float* __restrict__ W,
                                                     unsigned short* __restrict__ Wt,
                                                     int K, int N) {
    tp_body(W, Wt, K, N, blockIdx.x, blockIdx.y, threadIdx.x);
}

// 4 same-shape (1024x1024) weights in one launch
__global__ __launch_bounds__(256) void transpose_cvt4(const float* W0, const float* W1,
                                                      const float* W2, const float* W3,
                                                      unsigned short* T0, unsigned short* T1,
                                                      unsigned short* T2, unsigned short* T3) {
    const float* W = (blockIdx.z == 0) ? W0 : (blockIdx.z == 1) ? W1 : (blockIdx.z == 2) ? W2 : W3;
    unsigned short* T = (blockIdx.z == 0) ? T0 : (blockIdx.z == 1) ? T1 : (blockIdx.z == 2) ? T2 : T3;
    tp_body(W, T, DD, DD, blockIdx.x, blockIdx.y, threadIdx.x);
}

// 2 same-shape (1024x4096) weights in one launch
__global__ __launch_bounds__(256) void transpose_cvt2(const float* W0, const float* W1,
                                                      unsigned short* T0, unsigned short* T1) {
    const float* W = (blockIdx.z == 0) ? W0 : W1;
    unsigned short* T = (blockIdx.z == 0) ? T0 : T1;
    tp_body(W, T, DD, FF, blockIdx.x, blockIdx.y, threadIdx.x);
}

// Wb [1024][16] fp32 -> WbT [16][1024] bf16
__global__ __launch_bounds__(256) void wbt_kernel(const float* __restrict__ Wb,
                                                  unsigned short* __restrict__ WbT) {
    int idx = blockIdx.x * 256 + threadIdx.x;  // 0..16383
    int d = idx >> 4, h = idx & 15;
    WbT[h * DD + d] = f2bf(Wb[idx]);
}

// ---------------- RMSNorm (D=1024) -> bf16 ----------------
__global__ __launch_bounds__(256) void rmsnorm_bf16_kernel(const float* __restrict__ src,
                                                           const float* __restrict__ w,
                                                           unsigned short* __restrict__ dst) {
    int row = blockIdx.x;
    int tid = threadIdx.x;
    float4 x = ((const float4*)(src + (size_t)row * DD))[tid];
    float ss = x.x * x.x + x.y * x.y + x.z * x.z + x.w * x.w;
#pragma unroll
    for (int m = 1; m < 64; m <<= 1) ss += __shfl_xor(ss, m, 64);
    __shared__ float ws4[4];
    if ((tid & 63) == 0) ws4[tid >> 6] = ss;
    __syncthreads();
    ss = ws4[0] + ws4[1] + ws4[2] + ws4[3];
    float sc = rsqrtf(ss * (1.f / DD) + 1e-6f);
    float4 wv = ((const float4*)w)[tid];
    ushort4 o;
    o.x = f2bf(x.x * sc * wv.x);
    o.y = f2bf(x.y * sc * wv.y);
    o.z = f2bf(x.z * sc * wv.z);
    o.w = f2bf(x.w * sc * wv.w);
    ((ushort4*)(dst + (size_t)row * DD))[tid] = o;
}

// ---------------- bf16 GEMM: C[M][N] = A[M][K] * Bt[N][K]^T ----------------
// EP 1: fp32 out + fp32 residual; EP 2: bf16 out; EP 3: fused QKV+beta split epilogue
#define BM 128
#define BN 128
#define BK 32

template <int EP>
__global__ __launch_bounds__(256) void gemm_bt(const unsigned short* __restrict__ A,
                                               const unsigned short* __restrict__ Bt,
                                               const float* __restrict__ res,
                                               float* __restrict__ cf,
                                               unsigned short* __restrict__ cb,
                                               int M, int N, int K) {
    __shared__ __align__(16) char sA[BM * BK * 2];
    __shared__ __align__(16) char sB[BN * BK * 2];
    int m0 = blockIdx.y * BM, n0 = blockIdx.x * BN;
    int tid = threadIdx.x;
    int lane = tid & 63, wave = tid >> 6;
    int wm = wave >> 1, wn = wave & 1;  // 2x2 waves, each does 64x64
    f32x4 acc[4][4] = {};

    for (int k0 = 0; k0 < K; k0 += BK) {
#pragma unroll
        for (int i = 0; i < 2; ++i) {
            int c = wave * 2 + i;                 // chunk 0..7, 1KB each (16 rows of 64B)
            int row = c * 16 + (lane >> 2);
            int col = (lane & 3) * 8;             // bf16 elements
            gload16(A  + ((size_t)(m0 + row) * K + k0 + col), (char*)sA + c * 1024);
            gload16(Bt + ((size_t)(n0 + row) * K + k0 + col), (char*)sB + c * 1024);
        }
        __syncthreads();
        bf16x8 af[4], bfr[4];
#pragma unroll
        for (int mi = 0; mi < 4; ++mi) {
            int ar = wm * 64 + mi * 16 + (lane & 15);
            af[mi] = *(const bf16x8*)(sA + ar * 64 + (lane >> 4) * 16);
        }
#pragma unroll
        for (int ni = 0; ni < 4; ++ni) {
            int br = wn * 64 + ni * 16 + (lane & 15);
            bfr[ni] = *(const bf16x8*)(sB + br * 64 + (lane >> 4) * 16);
        }
#pragma unroll
        for (int mi = 0; mi < 4; ++mi)
#pragma unroll
            for (int ni = 0; ni < 4; ++ni)
                acc[mi][ni] = __builtin_amdgcn_mfma_f32_16x16x32_bf16(af[mi], bfr[ni], acc[mi][ni], 0, 0, 0);
        __syncthreads();
    }

    int mbase = m0 + wm * 64 + (lane >> 4) * 4;
    int nbase = n0 + wn * 64 + (lane & 15);
#pragma unroll
    for (int mi = 0; mi < 4; ++mi)
#pragma unroll
        for (int ni = 0; ni < 4; ++ni)
#pragma unroll
            for (int r = 0; r < 4; ++r) {
                int m = mbase + mi * 16 + r;
                int n = nbase + ni * 16;
                float v = acc[mi][ni][r];
                if (EP == 3) {
                    // n<3072: q/k/v (bf16, three contiguous [ROWS][DD] buffers)
                    // n>=3072: beta head = n-3072, only <16 valid (pad cols discarded)
                    int seg = n >> 10, col = n & 1023;
                    if (seg < 3)
                        cb[(size_t)seg * ROWS * DD + (size_t)m * DD + col] = f2bf(v);
                    else if (col < 16)
                        cf[(size_t)m * HH + col] = sigmoidf_(v);
                } else {
                    if (EP == 1) v += res[(size_t)m * N + n];
                    if (EP == 2) cb[(size_t)m * N + n] = f2bf(v);
                    else         cf[(size_t)m * N + n] = v;
                }
            }
}

// ---------------- act = silu(g) * u, bf16 in-place on g ----------------
__global__ void silu_mul_kernel(unsigned short* __restrict__ g, const unsigned short* __restrict__ u, int n4) {
    int i = blockIdx.x * blockDim.x + threadIdx.x;
    int stride = gridDim.x * blockDim.x;
    ushort4* gp = (ushort4*)g;
    const ushort4* up = (const ushort4*)u;
    for (; i < n4; i += stride) {
        ushort4 gv = gp[i];
        ushort4 uv = up[i];
        ushort4 o;
        o.x = f2bf(siluf_(bf2f(gv.x)) * bf2f(uv.x));
        o.y = f2bf(siluf_(bf2f(gv.y)) * bf2f(uv.y));
        o.z = f2bf(siluf_(bf2f(gv.z)) * bf2f(uv.z));
        o.w = f2bf(siluf_(bf2f(gv.w)) * bf2f(uv.w));
        gp[i] = o;
    }
}

// ================= chunked delta rule =================
// Per-chunk matrices are 64x64. MFMA op(X,Y)[m][n] = sum_k X[m][k]*Y[n][k]
// (both operands read row-major, [idx][k], idx = lane&15).
// D-layout: n = lane&15, m = 16*tile_m + (lane>>4)*4 + r.

__device__ __forceinline__ bf16x8 ldsfrag(const char* mat, int row, int kt, int lane) {
    return *(const bf16x8*)(mat + swz(row * 128 + kt * 64 + (lane >> 4) * 16));
}

// generic 64x64x64 matmul on swizzled LDS bf16 matrices; wave w owns m-rows [16w,16w+16)
template <bool INIT_P>
__device__ __forceinline__ void mm64(const char* X, const char* Y, const char* P,
                                     f32x4 acc[4], int w, int lane) {
    int g = lane >> 4;
#pragma unroll
    for (int j = 0; j < 4; ++j) {
        if (INIT_P) {
#pragma unroll
            for (int r = 0; r < 4; ++r) {
                int m = 16 * w + g * 4 + r, n = (lane & 15) + 16 * j;
                acc[j][r] = bf2f(*(const unsigned short*)(P + swz(m * 128 + n * 2)));
            }
        } else {
            acc[j] = (f32x4){0.f, 0.f, 0.f, 0.f};
        }
    }
    bf16x8 xs0 = ldsfrag(X, 16 * w + (lane & 15), 0, lane);
    bf16x8 xs1 = ldsfrag(X, 16 * w + (lane & 15), 1, lane);
#pragma unroll
    for (int j = 0; j < 4; ++j) {
        bf16x8 y0 = ldsfrag(Y, 16 * j + (lane & 15), 0, lane);
        bf16x8 y1 = ldsfrag(Y, 16 * j + (lane & 15), 1, lane);
        acc[j] = __builtin_amdgcn_mfma_f32_16x16x32_bf16(xs0, y0, acc[j], 0, 0, 0);
        acc[j] = __builtin_amdgcn_mfma_f32_16x16x32_bf16(xs1, y1, acc[j], 0, 0, 0);
    }
}

// row-major LDS write. mode: 0 plain, 1 strict-lower (keep n<m), 2 P1 = I - strict(L)
__device__ __forceinline__ void wR(char* D, const f32x4 acc[4], int w, int lane, int mode) {
    int g = lane >> 4;
#pragma unroll
    for (int j = 0; j < 4; ++j)
#pragma unroll
        for (int r = 0; r < 4; ++r) {
            int m = 16 * w + g * 4 + r, n = (lane & 15) + 16 * j;
            float v = acc[j][r];
            if (mode >= 1) v = (n < m) ? v : 0.f;
            if (mode == 2) v = ((m == n) ? 1.f : 0.f) - v;
            *(unsigned short*)(D + swz(m * 128 + n * 2)) = f2bf(v);
        }
}

// transposed packed LDS write: D[n][m0..m0+3]. mode: 0 plain, 1 strict (keep n<m)
__device__ __forceinline__ void wT(char* D, const f32x4 acc[4], int w, int lane, int mode) {
    int g = lane >> 4;
#pragma unroll
    for (int j = 0; j < 4; ++j) {
        int n = (lane & 15) + 16 * j, m0 = 16 * w + g * 4;
        ushort4 pk;
        pk.x = (mode == 1 && !(n < m0 + 0)) ? (unsigned short)0 : f2bf(acc[j][0]);
        pk.y = (mode == 1 && !(n < m0 + 1)) ? (unsigned short)0 : f2bf(acc[j][1]);
        pk.z = (mode == 1 && !(n < m0 + 2)) ? (unsigned short)0 : f2bf(acc[j][2]);
        pk.w = (mode == 1 && !(n < m0 + 3)) ? (unsigned short)0 : f2bf(acc[j][3]);
        *(ushort4*)(D + swz(n * 128 + m0 * 2)) = pk;
    }
}

__device__ __forceinline__ void load16bf(const unsigned short* p, float* v) {
    uint4 a = *(const uint4*)p, b = *(const uint4*)(p + 8);
    unsigned int u0[8] = {a.x, a.y, a.z, a.w, b.x, b.y, b.z, b.w};
#pragma unroll
    for (int i = 0; i < 8; ++i) {
        v[2 * i]     = bf2f((unsigned short)(u0[i] & 0xffffu));
        v[2 * i + 1] = bf2f((unsigned short)(u0[i] >> 16));
    }
}

// -------- parallel per-chunk prep: silu/l2norm/beta-scale + T=(I+L)^-1 + outputs --------
// grid: 1024 blocks = (b,h,c); 256 threads. Outputs per chunk (40KB):
//   Q[t][dk] bf16 | KT[dk][t] bf16 | A[t][s] bf16 (incl-tril QK^T) | W[t][dk]=T*K_b | U0T[dv][t]=(T*V_b)^T
__global__ __launch_bounds__(256) void delta_prep_kernel(const unsigned short* __restrict__ qb,
                                                         const unsigned short* __restrict__ kb,
                                                         const unsigned short* __restrict__ vb,
                                                         const float* __restrict__ betab,
                                                         char* __restrict__ chunkbuf) {
    __shared__ __align__(16) char sK[8192], sKb[8192], sKbT[8192], sVbT[8192], sQ[8192];
    __shared__ __align__(16) char mA[8192], mAT[8192], mB2[8192], mBT[8192], mP0[8192], mP1[8192];

    int ci = blockIdx.x;
    int c = ci & 31, h = (ci >> 5) & 15, b = ci >> 9;
    int tid = threadIdx.x;
    int lane = tid & 63, w = tid >> 6;

    char* cbuf = chunkbuf + (size_t)ci * 40960;
    unsigned short* Qg  = (unsigned short*)(cbuf);
    unsigned short* KTg = (unsigned short*)(cbuf + 8192);
    unsigned short* Ag  = (unsigned short*)(cbuf + 16384);
    unsigned short* Wg  = (unsigned short*)(cbuf + 24576);
    unsigned short* U0g = (unsigned short*)(cbuf + 32768);

    // ---- staging: 4 threads per row, 16 elems each ----
    {
        int trow = tid >> 2, part = tid & 3, d0 = part * 16;
        size_t rg = (size_t)b * SS + c * 64 + trow;
        float bet = betab[rg * HH + h];
        size_t base = rg * DD + h * 64 + d0;

        float qv[16], kv[16], vv[16];
        load16bf(qb + base, qv);
        load16bf(kb + base, kv);
        load16bf(vb + base, vv);

        float ssq = 0.f, ssk = 0.f;
#pragma unroll
        for (int i = 0; i < 16; ++i) {
            qv[i] = siluf_(qv[i]); ssq += qv[i] * qv[i];
            kv[i] = siluf_(kv[i]); ssk += kv[i] * kv[i];
            vv[i] = siluf_(vv[i]);
        }
        ssq += __shfl_xor(ssq, 1, 64); ssq += __shfl_xor(ssq, 2, 64);
        ssk += __shfl_xor(ssk, 1, 64); ssk += __shfl_xor(ssk, 2, 64);
        float scq = rsqrtf(ssq + 1e-6f), sck = rsqrtf(ssk + 1e-6f);
#pragma unroll
        for (int i = 0; i < 16; ++i) { qv[i] *= scq; kv[i] *= sck; }

        // packed swizzled LDS writes (4x ushort4 per matrix) + global Q
#pragma unroll
        for (int m = 0; m < 4; ++m) {
            ushort4 pq, pk_, pkb;
#pragma unroll
            for (int r = 0; r < 4; ++r) {
                ((unsigned short*)&pq)[r]  = f2bf(qv[4 * m + r]);
                ((unsigned short*)&pk_)[r] = f2bf(kv[4 * m + r]);
                ((unsigned short*)&pkb)[r] = f2bf(bet * kv[4 * m + r]);
            }
            int bo = trow * 128 + (d0 + 4 * m) * 2;
            *(ushort4*)(sQ + swz(bo))  = pq;
            *(ushort4*)(sK + swz(bo))  = pk_;
            *(ushort4*)(sKb + swz(bo)) = pkb;
            *(ushort4*)(Qg + trow * 64 + d0 + 4 * m) = pq;
        }
        // scalar transposed writes: KbT, VbT (LDS), KT (global)
#pragma unroll
        for (int e = 0; e < 16; ++e) {
            int d = d0 + e;
            *(unsigned short*)(sKbT + swz(d * 128 + trow * 2)) = f2bf(bet * kv[e]);
            *(unsigned short*)(sVbT + swz(d * 128 + trow * 2)) = f2bf(bet * vv[e]);
            KTg[d * 64 + trow] = f2bf(kv[e]);
        }
    }
    __syncthreads();

    f32x4 acc[4];
    // L = strict_tril(K_b K^T); P1 = I - L
    mm64<false>(sKb, sK, nullptr, acc, w, lane);
    wR(mA, acc, w, lane, 1);   // L
    wT(mAT, acc, w, lane, 1);  // L^T
    wR(mP0, acc, w, lane, 2);  // P1
    __syncthreads();

    // T = (I-L)(I+L^2)(I+L^4)(I+L^8)(I+L^16)(I+L^32)
    char *cX = mA, *cXT = mAT, *nX = mB2, *nXT = mBT, *pc = mP0, *pn = mP1;
#pragma unroll
    for (int s = 0; s < 5; ++s) {
        mm64<false>(cX, cXT, nullptr, acc, w, lane);   // next power = cur^2
        wR(nX, acc, w, lane, 0);
        wT(nXT, acc, w, lane, 0);
        __syncthreads();
        mm64<true>(pc, nXT, pc, acc, w, lane);         // P = P + P * power
        wR(pn, acc, w, lane, 0);
        __syncthreads();
        char* t;
        t = cX; cX = nX; nX = t;
        t = cXT; cXT = nXT; nXT = t;
        t = pc; pc = pn; pn = t;
    }
    // pc now holds T

    int g = lane >> 4;
    // A = incl_tril(Q K^T): R = op(K, Q) -> write transposed packed to global, keep s<=t
    mm64<false>(sK, sQ, nullptr, acc, w, lane);
#pragma unroll
    for (int j = 0; j < 4; ++j) {
        int n = (lane & 15) + 16 * j, m0 = 16 * w + g * 4;  // n=t, m=s
        ushort4 pk;
        pk.x = (m0 + 0 <= n) ? f2bf(acc[j][0]) : (unsigned short)0;
        pk.y = (m0 + 1 <= n) ? f2bf(acc[j][1]) : (unsigned short)0;
        pk.z = (m0 + 2 <= n) ? f2bf(acc[j][2]) : (unsigned short)0;
        pk.w = (m0 + 3 <= n) ? f2bf(acc[j][3]) : (unsigned short)0;
        *(ushort4*)(Ag + n * 64 + m0) = pk;
    }
    // W = T*K_b: R = op(KbT, T) gives W^T -> transposed write = W[t][dk]
    mm64<false>(sKbT, pc, nullptr, acc, w, lane);
#pragma unroll
    for (int j = 0; j < 4; ++j) {
        int n = (lane & 15) + 16 * j, m0 = 16 * w + g * 4;  // n=t, m=dk
        ushort4 pk;
        pk.x = f2bf(acc[j][0]); pk.y = f2bf(acc[j][1]);
        pk.z = f2bf(acc[j][2]); pk.w = f2bf(acc[j][3]);
        *(ushort4*)(Wg + n * 64 + m0) = pk;
    }
    // U0 = T*V_b: R = op(T, VbT) = U0[t][dv] -> transposed write = U0T[dv][t]
    mm64<false>(pc, sVbT, nullptr, acc, w, lane);
#pragma unroll
    for (int j = 0; j < 4; ++j) {
        int n = (lane & 15) + 16 * j, m0 = 16 * w + g * 4;  // n=dv, m=t
        ushort4 pk;
        pk.x = f2bf(acc[j][0]); pk.y = f2bf(acc[j][1]);
        pk.z = f2bf(acc[j][2]); pk.w = f2bf(acc[j][3]);
        *(ushort4*)(U0g + n * 64 + m0) = pk;
    }
}

// -------- sequential inter-chunk scan: 32 blocks = (b,h), 256 threads --------
// State S^T[dv][dk] in fp32 accs (wave w owns dv rows [16w,16w+16)) + bf16 LDS mirror.
// Per chunk: U^T = U0T - op(Sl,W); oT = op(Sl,Q) + op(UT,A); S^T += op(UT,KT).
__global__ __launch_bounds__(256) void delta_seq_kernel(const char* __restrict__ chunkbuf,
                                                        unsigned short* __restrict__ ob) {
    __shared__ __align__(16) char stg[2 * 40960 + 8192 + 8192];
    int bh = blockIdx.x;
    int b = bh >> 4, h = bh & 15;
    int tid = threadIdx.x;
    int lane = tid & 63, w = tid >> 6, g = lane >> 4;

    char* UTw = stg + 81920 + w * 2048;   // wave-private U^T slice [16][64] bf16 swz
    char* Slw = stg + 90112 + w * 2048;   // wave-private S^T slice [16][64] bf16 swz

    // zero S
    f32x4 s_acc[4];
#pragma unroll
    for (int j = 0; j < 4; ++j) s_acc[j] = (f32x4){0.f, 0.f, 0.f, 0.f};
    uint4 z4 = {0, 0, 0, 0};
    *(uint4*)(Slw + lane * 32) = z4;
    *(uint4*)(Slw + lane * 32 + 16) = z4;

    const char* cbase = chunkbuf + (size_t)bh * NC * 40960;
    int lo = (lane * 16) ^ ((lane >> 3) << 4);   // pre-swizzled source offset per lane
    int pw = 10 * w;

    // prologue: stage chunk 0 into buffer 0
    {
        const char* src = cbase;
        char* dst = stg;
#pragma unroll
        for (int p = 0; p < 10; ++p)
            gload16(src + (pw + p) * 1024 + lo, dst + (pw + p) * 1024);
    }

    for (int c = 0; c < NC; ++c) {
        // issue prefetch for next chunk (wraps harmlessly at c=31)
        {
            const char* src = cbase + (size_t)((c + 1) & 31) * 40960;
            char* dst = stg + ((c + 1) & 1) * 40960;
#pragma unroll
            for (int p = 0; p < 10; ++p)
                gload16(src + (pw + p) * 1024 + lo, dst + (pw + p) * 1024);
        }
        asm volatile("s_waitcnt vmcnt(10)" ::: "memory");
        __builtin_amdgcn_s_barrier();
        __builtin_amdgcn_sched_barrier(0);

        const char* cur = stg + (c & 1) * 40960;
        const char* Qm = cur, *KTm = cur + 8192, *Am = cur + 16384, *Wm = cur + 24576, *U0m = cur + 32768;

        // X-frags from wave-private S^T
        bf16x8 xs0 = ldsfrag(Slw, lane & 15, 0, lane);
        bf16x8 xs1 = ldsfrag(Slw, lane & 15, 1, lane);

        // M1: ut = op(Sl, W)   (to be subtracted from U0T)
        f32x4 ut[4];
        f32x4 oa[4];
#pragma unroll
        for (int j = 0; j < 4; ++j) { ut[j] = (f32x4){0.f, 0.f, 0.f, 0.f}; oa[j] = (f32x4){0.f, 0.f, 0.f, 0.f}; }
#pragma unroll
        for (int j = 0; j < 4; ++j) {
            bf16x8 y0 = ldsfrag(Wm, 16 * j + (lane & 15), 0, lane);
            bf16x8 y1 = ldsfrag(Wm, 16 * j + (lane & 15), 1, lane);
            ut[j] = __builtin_amdgcn_mfma_f32_16x16x32_bf16(xs0, y0, ut[j], 0, 0, 0);
            ut[j] = __builtin_amdgcn_mfma_f32_16x16x32_bf16(xs1, y1, ut[j], 0, 0, 0);
        }
        // M2a: oT = op(Sl, Q)
#pragma unroll
        for (int j = 0; j < 4; ++j) {
            bf16x8 y0 = ldsfrag(Qm, 16 * j + (lane & 15), 0, lane);
            bf16x8 y1 = ldsfrag(Qm, 16 * j + (lane & 15), 1, lane);
            oa[j] = __builtin_amdgcn_mfma_f32_16x16x32_bf16(xs0, y0, oa[j], 0, 0, 0);
            oa[j] = __builtin_amdgcn_mfma_f32_16x16x32_bf16(xs1, y1, oa[j], 0, 0, 0);
        }
        // finalize U^T = U0T - ut, write to wave-private LDS (bf16, swz)
#pragma unroll
        for (int j = 0; j < 4; ++j)
#pragma unroll
            for (int r = 0; r < 4; ++r) {
                int m = 16 * w + g * 4 + r;          // dv (global row in U0T)
                int n = (lane & 15) + 16 * j;        // t
                float u0 = bf2f(*(const unsigned short*)(U0m + swz(m * 128 + n * 2)));
                float u = u0 - ut[j][r];
                *(unsigned short*)(UTw + swz((g * 4 + r) * 128 + n * 2)) = f2bf(u);
            }
        // M2b + M3 (UT wave-private: no barrier needed; compiler orders ds ops)
        bf16x8 us0 = ldsfrag(UTw, lane & 15, 0, lane);
        bf16x8 us1 = ldsfrag(UTw, lane & 15, 1, lane);
#pragma unroll
        for (int j = 0; j < 4; ++j) {
            bf16x8 y0 = ldsfrag(Am, 16 * j + (lane & 15), 0, lane);
            bf16x8 y1 = ldsfrag(Am, 16 * j + (lane & 15), 1, lane);
            oa[j] = __builtin_amdgcn_mfma_f32_16x16x32_bf16(us0, y0, oa[j], 0, 0, 0);
            oa[j] = __builtin_amdgcn_mfma_f32_16x16x32_bf16(us1, y1, oa[j], 0, 0, 0);
        }
#pragma unroll
        for (int j = 0; j < 4; ++j) {
            bf16x8 y0 = ldsfrag(KTm, 16 * j + (lane & 15), 0, lane);
            bf16x8 y1 = ldsfrag(KTm, 16 * j + (lane & 15), 1, lane);
            s_acc[j] = __builtin_amdgcn_mfma_f32_16x16x32_bf16(us0, y0, s_acc[j], 0, 0, 0);
            s_acc[j] = __builtin_amdgcn_mfma_f32_16x16x32_bf16(us1, y1, s_acc[j], 0, 0, 0);
        }
        // o store: oT[dv][t] -> transposed packed global o[t][h*64+dv..+3] bf16
#pragma unroll
        for (int j = 0; j < 4; ++j) {
            int n = (lane & 15) + 16 * j;            // t local
            size_t tg = (size_t)b * SS + c * 64 + n;
            int col = h * 64 + 16 * w + g * 4;
            ushort4 pk;
            pk.x = f2bf(oa[j][0]); pk.y = f2bf(oa[j][1]);
            pk.z = f2bf(oa[j][2]); pk.w = f2bf(oa[j][3]);
            *(ushort4*)(ob + tg * DD + col) = pk;
        }
        // refresh bf16 S mirror from fp32 accs (wave-private)
#pragma unroll
        for (int j = 0; j < 4; ++j)
#pragma unroll
            for (int r = 0; r < 4; ++r) {
                int n = (lane & 15) + 16 * j;        // dk
                *(unsigned short*)(Slw + swz((g * 4 + r) * 128 + n * 2)) = f2bf(s_acc[j][r]);
            }

        asm volatile("" ::: "memory");
        __builtin_amdgcn_s_barrier();   // all waves done reading cur before it is re-staged
        __builtin_amdgcn_sched_barrier(0);
    }
}

// ---------------- launch ----------------
extern "C" void kernel_launch(void* const* d_in, const int* in_sizes, int n_in,
                              void* d_out, int out_size, void* d_ws, size_t ws_size,
                              hipStream_t stream) {
    const float* hidden = (const float*)d_in[0];
    const float* Wq  = (const float*)d_in[1];
    const float* Wk  = (const float*)d_in[2];
    const float* Wv  = (const float*)d_in[3];
    const float* Wb  = (const float*)d_in[4];
    const float* Wo  = (const float*)d_in[5];
    const float* ln1 = (const float*)d_in[6];
    const float* ln2 = (const float*)d_in[7];
    const float* Wg  = (const float*)d_in[8];
    const float* Wu  = (const float*)d_in[9];
    const float* Wd  = (const float*)d_in[10];
    float* out = (float*)d_out;
    char* ws = (char*)d_ws;

    const size_t MB = 1024 * 1024;
    const size_t KB256 = 262144;
    // Bt for fused QKV+beta GEMM: rows 0..1023 wq | 1024..2047 wk | 2048..3071 wv | 3072..3087 WbT (pad to 3200)
    unsigned short* wq_t = (unsigned short*)(ws + 0 * MB);            // 2MB
    unsigned short* wk_t = (unsigned short*)(ws + 2 * MB);            // 2MB
    unsigned short* wv_t = (unsigned short*)(ws + 4 * MB);            // 2MB
    unsigned short* wbT  = (unsigned short*)(ws + 6 * MB);            // rows 3072..3199 (0.25MB)
    unsigned short* wo_t = (unsigned short*)(ws + 6 * MB + KB256);    // 2MB
    unsigned short* wg_t = (unsigned short*)(ws + 8 * MB + KB256);    // 8MB
    unsigned short* wu_t = (unsigned short*)(ws + 16 * MB + KB256);   // 8MB
    unsigned short* wd_t = (unsigned short*)(ws + 24 * MB + KB256);   // 8MB
    float* hbuf          = (float*)(ws + 32 * MB + KB256);            // 16MB fp32
    unsigned short* yb   = (unsigned short*)(ws + 48 * MB + KB256);   // 8MB
    unsigned short* qb   = (unsigned short*)(ws + 56 * MB + KB256);   // 8MB  (q,k,v contiguous!)
    unsigned short* kb   = (unsigned short*)(ws + 64 * MB + KB256);   // 8MB
    unsigned short* vb   = (unsigned short*)(ws + 72 * MB + KB256);   // 8MB
    float* betab         = (float*)(ws + 80 * MB + KB256);            // 0.25MB
    unsigned short* xb   = (unsigned short*)(ws + 80 * MB + 2 * KB256); // 8MB (dead after QKV gemm)
    unsigned short* ob   = xb;                                        // alias: ob reuses xb region
    char* chunkbuf       = ws + 88 * MB + 2 * KB256;                  // 40MB -> total 128.5MB
    // aliases for MLP stage (dead regions after delta):
    unsigned short* gb = (unsigned short*)(ws + 56 * MB + KB256);     // 32MB over qb..ob
    unsigned short* ub = (unsigned short*)(ws + 88 * MB + 2 * KB256); // 32MB over chunkbuf

    dim3 blk(256);

    // weights: fp32 [K][N] -> bf16 [N][K]
    transpose_cvt4<<<dim3(32, 32, 4), blk, 0, stream>>>(Wq, Wk, Wv, Wo, wq_t, wk_t, wv_t, wo_t);
    transpose_cvt2<<<dim3(128, 32, 2), blk, 0, stream>>>(Wg, Wu, wg_t, wu_t);
    transpose_cvt<<<dim3(32, 128), blk, 0, stream>>>(Wd, wd_t, FF, DD);
    wbt_kernel<<<64, blk, 0, stream>>>(Wb, wbT);

    rmsnorm_bf16_kernel<<<ROWS, blk, 0, stream>>>(hidden, ln1, xb);

    // fused Q/K/V/beta GEMM: N = 3200 (pad cols 3088..3199 discarded in epilogue)
    gemm_bt<3><<<dim3(NQKV / BN, ROWS / BM), blk, 0, stream>>>(xb, wq_t, nullptr, betab, qb, ROWS, NQKV, DD);

    delta_prep_kernel<<<1024, blk, 0, stream>>>(qb, kb, vb, betab, chunkbuf);
    delta_seq_kernel<<<BB * HH, blk, 0, stream>>>(chunkbuf, ob);

    gemm_bt<1><<<dim3(DD / BN, ROWS / BM), blk, 0, stream>>>(ob, wo_t, hidden, hbuf, nullptr, ROWS, DD, DD);

    rmsnorm_bf16_kernel<<<ROWS, blk, 0, stream>>>(hbuf, ln2, yb);

    gemm_bt<2><<<dim3(FF / BN, ROWS / BM), blk, 0, stream>>>(yb, wg_t, nullptr, nullptr, gb, ROWS, FF, DD);
    gemm_bt<2><<<dim3(FF / BN, ROWS / BM), blk, 0, stream>>>(yb, wu_t, nullptr, nullptr, ub, ROWS, FF, DD);

    silu_mul_kernel<<<4096, blk, 0, stream>>>(gb, ub, ROWS * FF / 4);

    gemm_bt<1><<<dim3(DD / BN, ROWS / BM), blk, 0, stream>>>(gb, wd_t, hbuf, out, nullptr, ROWS, DD, FF);
}

// Round 4
// 464.249 us; speedup vs baseline: 4.3071x; 1.1956x over previous
//
#include <hip/hip_runtime.h>
#include <hip/hip_bf16.h>
#include <stdint.h>

// Problem constants (B,S,D,F,H fixed by the reference)
#define BB 2
#define SS 2048
#define DD 1024
#define FF 4096
#define HH 16
#define ROWS (BB*SS)   // 4096
#define NC 32          // chunks per (b,h)  (2048/64)
#define NQKV 3200      // 3*1024 (q,k,v) + 16 (beta) padded to mult of 128

typedef float f32x4 __attribute__((ext_vector_type(4)));
typedef __bf16 bf16x8 __attribute__((ext_vector_type(8)));

typedef __attribute__((address_space(1))) const void* gas1p;
typedef __attribute__((address_space(3))) void* las3p;

__device__ __forceinline__ void gload16(const void* g, void* l) {
    // wave-uniform LDS base; HW scatters lane i at base + i*16; global addr is per-lane
    __builtin_amdgcn_global_load_lds((gas1p)g, (las3p)l, 16, 0, 0);
}

__device__ __forceinline__ unsigned short f2bf(float f) {
    unsigned int u = __builtin_bit_cast(unsigned int, f);
    u += 0x7fffu + ((u >> 16) & 1u);   // round-to-nearest-even
    return (unsigned short)(u >> 16);
}
__device__ __forceinline__ float bf2f(unsigned short s) {
    unsigned int u = ((unsigned int)s) << 16;
    return __builtin_bit_cast(float, u);
}
__device__ __forceinline__ float sigmoidf_(float x) { return 1.f / (1.f + __expf(-x)); }
__device__ __forceinline__ float siluf_(float x)    { return x / (1.f + __expf(-x)); }

// XOR swizzle for 64x64 bf16 (128B-row) LDS tiles: spreads the 16-way bank conflict
__device__ __forceinline__ int swz(int b) { return b ^ (((b >> 7) & 7) << 4); }

// ---------------- transpose + fp32->bf16 convert: W[K][N] -> Wt[N][K] ----------------
__device__ __forceinline__ void tp_body(const float* __restrict__ W,
                                        unsigned short* __restrict__ Wt,
                                        int K, int N, int bx, int by, int tid) {
    __shared__ float tile[32][33];
    int tx = tid & 31, ty = tid >> 5; // ty 0..7
    int n0 = bx * 32, k0 = by * 32;
#pragma unroll
    for (int i = 0; i < 4; ++i)
        tile[ty + 8 * i][tx] = W[(size_t)(k0 + ty + 8 * i) * N + n0 + tx];
    __syncthreads();
#pragma unroll
    for (int i = 0; i < 4; ++i)
        Wt[(size_t)(n0 + ty + 8 * i) * K + k0 + tx] = f2bf(tile[tx][ty + 8 * i]);
}

__global__ __launch_bounds__(256) void transpose_cvt(const float* __restrict__ W,
                                                     unsigned short* __restrict__ Wt,
                                                     int K, int N) {
    tp_body(W, Wt, K, N, blockIdx.x, blockIdx.y, threadIdx.x);
}

// 4 same-shape (1024x1024) weights in one launch
__global__ __launch_bounds__(256) void transpose_cvt4(const float* W0, const float* W1,
                                                      const float* W2, const float* W3,
                                                      unsigned short* T0, unsigned short* T1,
                                                      unsigned short* T2, unsigned short* T3) {
    const float* W = (blockIdx.z == 0) ? W0 : (blockIdx.z == 1) ? W1 : (blockIdx.z == 2) ? W2 : W3;
    unsigned short* T = (blockIdx.z == 0) ? T0 : (blockIdx.z == 1) ? T1 : (blockIdx.z == 2) ? T2 : T3;
    tp_body(W, T, DD, DD, blockIdx.x, blockIdx.y, threadIdx.x);
}

// Wg/Wu (1024x4096) -> interleaved BtGU [8192][1024]:
// group gi (16 cols of F): rows 32gi..32gi+15 = Wg cols, rows 32gi+16..+31 = Wu cols
__global__ __launch_bounds__(256) void transpose_cvt_gu(const float* W0, const float* W1,
                                                        unsigned short* Wt) {
    const float* W = (blockIdx.z == 0) ? W0 : W1;
    int isU = blockIdx.z;
    __shared__ float tile[32][33];
    int tid = threadIdx.x;
    int tx = tid & 31, ty = tid >> 5;
    int n0 = blockIdx.x * 32, k0 = blockIdx.y * 32;
#pragma unroll
    for (int i = 0; i < 4; ++i)
        tile[ty + 8 * i][tx] = W[(size_t)(k0 + ty + 8 * i) * FF + n0 + tx];
    __syncthreads();
#pragma unroll
    for (int i = 0; i < 4; ++i) {
        int j = n0 + ty + 8 * i;
        int rint = ((j >> 4) << 5) + (j & 15) + (isU << 4);
        Wt[(size_t)rint * DD + k0 + tx] = f2bf(tile[tx][ty + 8 * i]);
    }
}

// Wb [1024][16] fp32 -> WbT [16][1024] bf16
__global__ __launch_bounds__(256) void wbt_kernel(const float* __restrict__ Wb,
                                                  unsigned short* __restrict__ WbT) {
    int idx = blockIdx.x * 256 + threadIdx.x;  // 0..16383
    int d = idx >> 4, h = idx & 15;
    WbT[h * DD + d] = f2bf(Wb[idx]);
}

// ---------------- RMSNorm (D=1024) -> bf16 ----------------
__global__ __launch_bounds__(256) void rmsnorm_bf16_kernel(const float* __restrict__ src,
                                                           const float* __restrict__ w,
                                                           unsigned short* __restrict__ dst) {
    int row = blockIdx.x;
    int tid = threadIdx.x;
    float4 x = ((const float4*)(src + (size_t)row * DD))[tid];
    float ss = x.x * x.x + x.y * x.y + x.z * x.z + x.w * x.w;
#pragma unroll
    for (int m = 1; m < 64; m <<= 1) ss += __shfl_xor(ss, m, 64);
    __shared__ float ws4[4];
    if ((tid & 63) == 0) ws4[tid >> 6] = ss;
    __syncthreads();
    ss = ws4[0] + ws4[1] + ws4[2] + ws4[3];
    float sc = rsqrtf(ss * (1.f / DD) + 1e-6f);
    float4 wv = ((const float4*)w)[tid];
    ushort4 o;
    o.x = f2bf(x.x * sc * wv.x);
    o.y = f2bf(x.y * sc * wv.y);
    o.z = f2bf(x.z * sc * wv.z);
    o.w = f2bf(x.w * sc * wv.w);
    ((ushort4*)(dst + (size_t)row * DD))[tid] = o;
}

// ---------------- 2-phase double-buffered bf16 GEMM ----------------
// C[M][N] = A[M][K] * Bt[N][K]^T.  BK=64, dbuf LDS, one __syncthreads per K-step.
// EP 1: fp32 out + fp32 residual
// EP 2: bf16 out
// EP 3: fused QKV+beta split epilogue (cb = q|k|v bufs, cf = beta)
// EP 4: fused GU: Bt is 16-interleaved g/u rows; writes act[m][j]=silu(g)*u bf16 (ld FF)
template <int EP, int BMt, int BNt, int WM, int WN, bool FASTM>
__global__ __launch_bounds__(WM * WN * 64) void gemm2(const unsigned short* __restrict__ A,
                                                      const unsigned short* __restrict__ Bt,
                                                      const float* __restrict__ res,
                                                      float* __restrict__ cf,
                                                      unsigned short* __restrict__ cb,
                                                      int M, int N, int K) {
    constexpr int NW = WM * WN;
    constexpr int MI = BMt / (WM * 16);
    constexpr int NI = BNt / (WN * 16);
    constexpr int ACH = BMt / 8 / NW;     // 1KB chunks per wave (A)
    constexpr int BCH = BNt / 8 / NW;
    constexpr int ABYTES = BMt * 128;     // one K-tile of A (BK=64 bf16 = 128B rows)
    constexpr int BBYTES = BNt * 128;
    __shared__ __align__(16) char lds[2 * (ABYTES + BBYTES)];

    int tid = threadIdx.x, lane = tid & 63, w = tid >> 6;
    int wm = w / WN, wn = w % WN;

    // bijective XCD-chunked swizzle (m204)
    int gm = M / BMt, gn = N / BNt, nwg = gm * gn;
    int flat = blockIdx.x;
    int q = nwg >> 3, r8 = nwg & 7;
    int xcd = flat & 7, loc = flat >> 3;
    int sid = (xcd < r8 ? xcd * (q + 1) : r8 * (q + 1) + (xcd - r8) * q) + loc;
    int midx, nidx;
    if (FASTM) { midx = sid % gm; nidx = sid / gm; }
    else       { nidx = sid % gn; midx = sid / gn; }
    int m0 = midx * BMt, n0 = nidx * BNt;

    auto stage = [&](int buf, int kt) {
        char* base = (char*)lds + buf * (ABYTES + BBYTES);
        int row8 = lane >> 3, col = (lane & 7) * 8;
#pragma unroll
        for (int i = 0; i < ACH; ++i) {
            int c = w * ACH + i;
            gload16(A + ((size_t)(m0 + c * 8 + row8) * K + kt * 64 + col), base + c * 1024);
        }
#pragma unroll
        for (int i = 0; i < BCH; ++i) {
            int c = w * BCH + i;
            gload16(Bt + ((size_t)(n0 + c * 8 + row8) * K + kt * 64 + col), base + ABYTES + c * 1024);
        }
    };

    f32x4 acc[MI][NI] = {};
    int nk = K / 64;
    stage(0, 0);
    __syncthreads();
    int cur = 0;
    for (int kt = 0; kt < nk; ++kt) {
        if (kt + 1 < nk) stage(cur ^ 1, kt + 1);   // async loads overlap this tile's MFMA
        const char* abuf = (const char*)lds + cur * (ABYTES + BBYTES);
        const char* bbuf = abuf + ABYTES;
#pragma unroll
        for (int kk = 0; kk < 2; ++kk) {
            bf16x8 afr[MI], bfr[NI];
#pragma unroll
            for (int mi = 0; mi < MI; ++mi)
                afr[mi] = *(const bf16x8*)(abuf + (wm * (MI * 16) + mi * 16 + (lane & 15)) * 128 + kk * 64 + (lane >> 4) * 16);
#pragma unroll
            for (int ni = 0; ni < NI; ++ni)
                bfr[ni] = *(const bf16x8*)(bbuf + (wn * (NI * 16) + ni * 16 + (lane & 15)) * 128 + kk * 64 + (lane >> 4) * 16);
#pragma unroll
            for (int mi = 0; mi < MI; ++mi)
#pragma unroll
                for (int ni = 0; ni < NI; ++ni)
                    acc[mi][ni] = __builtin_amdgcn_mfma_f32_16x16x32_bf16(afr[mi], bfr[ni], acc[mi][ni], 0, 0, 0);
        }
        if (kt + 1 < nk) {
            __syncthreads();   // drains vmcnt (staged tile ready) + all waves done reading cur
            cur ^= 1;
        }
    }

    int mbase = m0 + wm * (MI * 16) + (lane >> 4) * 4;
    if (EP == 4) {
        int j0 = (n0 + wn * (NI * 16)) / 2 + (lane & 15);
#pragma unroll
        for (int mi = 0; mi < MI; ++mi)
#pragma unroll
            for (int p = 0; p < NI / 2; ++p)
#pragma unroll
                for (int r = 0; r < 4; ++r) {
                    int m = mbase + mi * 16 + r;
                    float gv = acc[mi][2 * p][r], uv = acc[mi][2 * p + 1][r];
                    cb[(size_t)m * FF + j0 + 16 * p] = f2bf(siluf_(gv) * uv);
                }
    } else {
        int nbase = n0 + wn * (NI * 16) + (lane & 15);
#pragma unroll
        for (int mi = 0; mi < MI; ++mi)
#pragma unroll
            for (int ni = 0; ni < NI; ++ni)
#pragma unroll
                for (int r = 0; r < 4; ++r) {
                    int m = mbase + mi * 16 + r;
                    int n = nbase + ni * 16;
                    float v = acc[mi][ni][r];
                    if (EP == 3) {
                        int seg = n >> 10, col = n & 1023;
                        if (seg < 3)
                            cb[(size_t)seg * ROWS * DD + (size_t)m * DD + col] = f2bf(v);
                        else if (col < 16)
                            cf[(size_t)m * HH + col] = sigmoidf_(v);
                    } else {
                        if (EP == 1) v += res[(size_t)m * N + n];
                        if (EP == 2) cb[(size_t)m * N + n] = f2bf(v);
                        else         cf[(size_t)m * N + n] = v;
                    }
                }
    }
}

// ================= chunked delta rule =================
// Per-chunk matrices are 64x64. MFMA op(X,Y)[m][n] = sum_k X[m][k]*Y[n][k]
// (both operands read row-major, [idx][k], idx = lane&15).
// D-layout: n = lane&15, m = 16*tile_m + (lane>>4)*4 + r.

__device__ __forceinline__ bf16x8 ldsfrag(const char* mat, int row, int kt, int lane) {
    return *(const bf16x8*)(mat + swz(row * 128 + kt * 64 + (lane >> 4) * 16));
}

// generic 64x64x64 matmul on swizzled LDS bf16 matrices; wave w owns m-rows [16w,16w+16)
template <bool INIT_P>
__device__ __forceinline__ void mm64(const char* X, const char* Y, const char* P,
                                     f32x4 acc[4], int w, int lane) {
    int g = lane >> 4;
#pragma unroll
    for (int j = 0; j < 4; ++j) {
        if (INIT_P) {
#pragma unroll
            for (int r = 0; r < 4; ++r) {
                int m = 16 * w + g * 4 + r, n = (lane & 15) + 16 * j;
                acc[j][r] = bf2f(*(const unsigned short*)(P + swz(m * 128 + n * 2)));
            }
        } else {
            acc[j] = (f32x4){0.f, 0.f, 0.f, 0.f};
        }
    }
    bf16x8 xs0 = ldsfrag(X, 16 * w + (lane & 15), 0, lane);
    bf16x8 xs1 = ldsfrag(X, 16 * w + (lane & 15), 1, lane);
#pragma unroll
    for (int j = 0; j < 4; ++j) {
        bf16x8 y0 = ldsfrag(Y, 16 * j + (lane & 15), 0, lane);
        bf16x8 y1 = ldsfrag(Y, 16 * j + (lane & 15), 1, lane);
        acc[j] = __builtin_amdgcn_mfma_f32_16x16x32_bf16(xs0, y0, acc[j], 0, 0, 0);
        acc[j] = __builtin_amdgcn_mfma_f32_16x16x32_bf16(xs1, y1, acc[j], 0, 0, 0);
    }
}

// row-major LDS write. mode: 0 plain, 1 strict-lower (keep n<m), 2 P1 = I - strict(L)
__device__ __forceinline__ void wR(char* D, const f32x4 acc[4], int w, int lane, int mode) {
    int g = lane >> 4;
#pragma unroll
    for (int j = 0; j < 4; ++j)
#pragma unroll
        for (int r = 0; r < 4; ++r) {
            int m = 16 * w + g * 4 + r, n = (lane & 15) + 16 * j;
            float v = acc[j][r];
            if (mode >= 1) v = (n < m) ? v : 0.f;
            if (mode == 2) v = ((m == n) ? 1.f : 0.f) - v;
            *(unsigned short*)(D + swz(m * 128 + n * 2)) = f2bf(v);
        }
}

// transposed packed LDS write: D[n][m0..m0+3]. mode: 0 plain, 1 strict (keep n<m)
__device__ __forceinline__ void wT(char* D, const f32x4 acc[4], int w, int lane, int mode) {
    int g = lane >> 4;
#pragma unroll
    for (int j = 0; j < 4; ++j) {
        int n = (lane & 15) + 16 * j, m0 = 16 * w + g * 4;
        ushort4 pk;
        pk.x = (mode == 1 && !(n < m0 + 0)) ? (unsigned short)0 : f2bf(acc[j][0]);
        pk.y = (mode == 1 && !(n < m0 + 1)) ? (unsigned short)0 : f2bf(acc[j][1]);
        pk.z = (mode == 1 && !(n < m0 + 2)) ? (unsigned short)0 : f2bf(acc[j][2]);
        pk.w = (mode == 1 && !(n < m0 + 3)) ? (unsigned short)0 : f2bf(acc[j][3]);
        *(ushort4*)(D + swz(n * 128 + m0 * 2)) = pk;
    }
}

__device__ __forceinline__ void load16bf(const unsigned short* p, float* v) {
    uint4 a = *(const uint4*)p, b = *(const uint4*)(p + 8);
    unsigned int u0[8] = {a.x, a.y, a.z, a.w, b.x, b.y, b.z, b.w};
#pragma unroll
    for (int i = 0; i < 8; ++i) {
        v[2 * i]     = bf2f((unsigned short)(u0[i] & 0xffffu));
        v[2 * i + 1] = bf2f((unsigned short)(u0[i] >> 16));
    }
}

// -------- parallel per-chunk prep: silu/l2norm/beta-scale + T=(I+L)^-1 + outputs --------
// grid: 1024 blocks = (b,h,c); 256 threads. Outputs per chunk (40KB):
//   Q[t][dk] bf16 | KT[dk][t] bf16 | A[t][s] bf16 (incl-tril QK^T) | W[t][dk]=T*K_b | U0T[dv][t]=(T*V_b)^T
__global__ __launch_bounds__(256) void delta_prep_kernel(const unsigned short* __restrict__ qb,
                                                         const unsigned short* __restrict__ kb,
                                                         const unsigned short* __restrict__ vb,
                                                         const float* __restrict__ betab,
                                                         char* __restrict__ chunkbuf) {
    __shared__ __align__(16) char sK[8192], sKb[8192], sKbT[8192], sVbT[8192], sQ[8192];
    __shared__ __align__(16) char mA[8192], mAT[8192], mB2[8192], mBT[8192], mP0[8192], mP1[8192];

    int ci = blockIdx.x;
    int c = ci & 31, h = (ci >> 5) & 15, b = ci >> 9;
    int tid = threadIdx.x;
    int lane = tid & 63, w = tid >> 6;

    char* cbuf = chunkbuf + (size_t)ci * 40960;
    unsigned short* Qg  = (unsigned short*)(cbuf);
    unsigned short* KTg = (unsigned short*)(cbuf + 8192);
    unsigned short* Ag  = (unsigned short*)(cbuf + 16384);
    unsigned short* Wg  = (unsigned short*)(cbuf + 24576);
    unsigned short* U0g = (unsigned short*)(cbuf + 32768);

    // ---- staging: 4 threads per row, 16 elems each ----
    {
        int trow = tid >> 2, part = tid & 3, d0 = part * 16;
        size_t rg = (size_t)b * SS + c * 64 + trow;
        float bet = betab[rg * HH + h];
        size_t base = rg * DD + h * 64 + d0;

        float qv[16], kv[16], vv[16];
        load16bf(qb + base, qv);
        load16bf(kb + base, kv);
        load16bf(vb + base, vv);

        float ssq = 0.f, ssk = 0.f;
#pragma unroll
        for (int i = 0; i < 16; ++i) {
            qv[i] = siluf_(qv[i]); ssq += qv[i] * qv[i];
            kv[i] = siluf_(kv[i]); ssk += kv[i] * kv[i];
            vv[i] = siluf_(vv[i]);
        }
        ssq += __shfl_xor(ssq, 1, 64); ssq += __shfl_xor(ssq, 2, 64);
        ssk += __shfl_xor(ssk, 1, 64); ssk += __shfl_xor(ssk, 2, 64);
        float scq = rsqrtf(ssq + 1e-6f), sck = rsqrtf(ssk + 1e-6f);
#pragma unroll
        for (int i = 0; i < 16; ++i) { qv[i] *= scq; kv[i] *= sck; }

        // packed swizzled LDS writes (4x ushort4 per matrix) + global Q
#pragma unroll
        for (int m = 0; m < 4; ++m) {
            ushort4 pq, pk_, pkb;
#pragma unroll
            for (int r = 0; r < 4; ++r) {
                ((unsigned short*)&pq)[r]  = f2bf(qv[4 * m + r]);
                ((unsigned short*)&pk_)[r] = f2bf(kv[4 * m + r]);
                ((unsigned short*)&pkb)[r] = f2bf(bet * kv[4 * m + r]);
            }
            int bo = trow * 128 + (d0 + 4 * m) * 2;
            *(ushort4*)(sQ + swz(bo))  = pq;
            *(ushort4*)(sK + swz(bo))  = pk_;
            *(ushort4*)(sKb + swz(bo)) = pkb;
            *(ushort4*)(Qg + trow * 64 + d0 + 4 * m) = pq;
        }
        // scalar transposed writes: KbT, VbT (LDS), KT (global)
#pragma unroll
        for (int e = 0; e < 16; ++e) {
            int d = d0 + e;
            *(unsigned short*)(sKbT + swz(d * 128 + trow * 2)) = f2bf(bet * kv[e]);
            *(unsigned short*)(sVbT + swz(d * 128 + trow * 2)) = f2bf(bet * vv[e]);
            KTg[d * 64 + trow] = f2bf(kv[e]);
        }
    }
    __syncthreads();

    f32x4 acc[4];
    // L = strict_tril(K_b K^T); P1 = I - L
    mm64<false>(sKb, sK, nullptr, acc, w, lane);
    wR(mA, acc, w, lane, 1);   // L
    wT(mAT, acc, w, lane, 1);  // L^T
    wR(mP0, acc, w, lane, 2);  // P1
    __syncthreads();

    // T = (I-L)(I+L^2)(I+L^4)(I+L^8)(I+L^16)(I+L^32)
    char *cX = mA, *cXT = mAT, *nX = mB2, *nXT = mBT, *pc = mP0, *pn = mP1;
#pragma unroll
    for (int s = 0; s < 5; ++s) {
        mm64<false>(cX, cXT, nullptr, acc, w, lane);   // next power = cur^2
        wR(nX, acc, w, lane, 0);
        wT(nXT, acc, w, lane, 0);
        __syncthreads();
        mm64<true>(pc, nXT, pc, acc, w, lane);         // P = P + P * power
        wR(pn, acc, w, lane, 0);
        __syncthreads();
        char* t;
        t = cX; cX = nX; nX = t;
        t = cXT; cXT = nXT; nXT = t;
        t = pc; pc = pn; pn = t;
    }
    // pc now holds T

    int g = lane >> 4;
    // A = incl_tril(Q K^T): R = op(K, Q) -> write transposed packed to global, keep s<=t
    mm64<false>(sK, sQ, nullptr, acc, w, lane);
#pragma unroll
    for (int j = 0; j < 4; ++j) {
        int n = (lane & 15) + 16 * j, m0 = 16 * w + g * 4;  // n=t, m=s
        ushort4 pk;
        pk.x = (m0 + 0 <= n) ? f2bf(acc[j][0]) : (unsigned short)0;
        pk.y = (m0 + 1 <= n) ? f2bf(acc[j][1]) : (unsigned short)0;
        pk.z = (m0 + 2 <= n) ? f2bf(acc[j][2]) : (unsigned short)0;
        pk.w = (m0 + 3 <= n) ? f2bf(acc[j][3]) : (unsigned short)0;
        *(ushort4*)(Ag + n * 64 + m0) = pk;
    }
    // W = T*K_b: R = op(KbT, T) gives W^T -> transposed write = W[t][dk]
    mm64<false>(sKbT, pc, nullptr, acc, w, lane);
#pragma unroll
    for (int j = 0; j < 4; ++j) {
        int n = (lane & 15) + 16 * j, m0 = 16 * w + g * 4;  // n=t, m=dk
        ushort4 pk;
        pk.x = f2bf(acc[j][0]); pk.y = f2bf(acc[j][1]);
        pk.z = f2bf(acc[j][2]); pk.w = f2bf(acc[j][3]);
        *(ushort4*)(Wg + n * 64 + m0) = pk;
    }
    // U0 = T*V_b: R = op(T, VbT) = U0[t][dv] -> transposed write = U0T[dv][t]
    mm64<false>(pc, sVbT, nullptr, acc, w, lane);
#pragma unroll
    for (int j = 0; j < 4; ++j) {
        int n = (lane & 15) + 16 * j, m0 = 16 * w + g * 4;  // n=dv, m=t
        ushort4 pk;
        pk.x = f2bf(acc[j][0]); pk.y = f2bf(acc[j][1]);
        pk.z = f2bf(acc[j][2]); pk.w = f2bf(acc[j][3]);
        *(ushort4*)(U0g + n * 64 + m0) = pk;
    }
}

// -------- sequential inter-chunk scan: 32 blocks = (b,h), 256 threads --------
// State S^T[dv][dk] in fp32 accs (wave w owns dv rows [16w,16w+16)) + bf16 LDS mirror.
// Per chunk: U^T = U0T - op(Sl,W); oT = op(Sl,Q) + op(UT,A); S^T += op(UT,KT).
__global__ __launch_bounds__(256) void delta_seq_kernel(const char* __restrict__ chunkbuf,
                                                        unsigned short* __restrict__ ob) {
    __shared__ __align__(16) char stg[2 * 40960 + 8192 + 8192];
    int bh = blockIdx.x;
    int b = bh >> 4, h = bh & 15;
    int tid = threadIdx.x;
    int lane = tid & 63, w = tid >> 6, g = lane >> 4;

    char* UTw = stg + 81920 + w * 2048;   // wave-private U^T slice [16][64] bf16 swz
    char* Slw = stg + 90112 + w * 2048;   // wave-private S^T slice [16][64] bf16 swz

    // zero S
    f32x4 s_acc[4];
#pragma unroll
    for (int j = 0; j < 4; ++j) s_acc[j] = (f32x4){0.f, 0.f, 0.f, 0.f};
    uint4 z4 = {0, 0, 0, 0};
    *(uint4*)(Slw + lane * 32) = z4;
    *(uint4*)(Slw + lane * 32 + 16) = z4;

    const char* cbase = chunkbuf + (size_t)bh * NC * 40960;
    int lo = (lane * 16) ^ ((lane >> 3) << 4);   // pre-swizzled source offset per lane
    int pw = 10 * w;

    // prologue: stage chunk 0 into buffer 0
    {
        const char* src = cbase;
        char* dst = stg;
#pragma unroll
        for (int p = 0; p < 10; ++p)
            gload16(src + (pw + p) * 1024 + lo, dst + (pw + p) * 1024);
    }

    for (int c = 0; c < NC; ++c) {
        // issue prefetch for next chunk (wraps harmlessly at c=31)
        {
            const char* src = cbase + (size_t)((c + 1) & 31) * 40960;
            char* dst = stg + ((c + 1) & 1) * 40960;
#pragma unroll
            for (int p = 0; p < 10; ++p)
                gload16(src + (pw + p) * 1024 + lo, dst + (pw + p) * 1024);
        }
        asm volatile("s_waitcnt vmcnt(10)" ::: "memory");
        __builtin_amdgcn_s_barrier();
        __builtin_amdgcn_sched_barrier(0);

        const char* cur = stg + (c & 1) * 40960;
        const char* Qm = cur, *KTm = cur + 8192, *Am = cur + 16384, *Wm = cur + 24576, *U0m = cur + 32768;

        // X-frags from wave-private S^T
        bf16x8 xs0 = ldsfrag(Slw, lane & 15, 0, lane);
        bf16x8 xs1 = ldsfrag(Slw, lane & 15, 1, lane);

        // M1: ut = op(Sl, W)   (to be subtracted from U0T)
        f32x4 ut[4];
        f32x4 oa[4];
#pragma unroll
        for (int j = 0; j < 4; ++j) { ut[j] = (f32x4){0.f, 0.f, 0.f, 0.f}; oa[j] = (f32x4){0.f, 0.f, 0.f, 0.f}; }
#pragma unroll
        for (int j = 0; j < 4; ++j) {
            bf16x8 y0 = ldsfrag(Wm, 16 * j + (lane & 15), 0, lane);
            bf16x8 y1 = ldsfrag(Wm, 16 * j + (lane & 15), 1, lane);
            ut[j] = __builtin_amdgcn_mfma_f32_16x16x32_bf16(xs0, y0, ut[j], 0, 0, 0);
            ut[j] = __builtin_amdgcn_mfma_f32_16x16x32_bf16(xs1, y1, ut[j], 0, 0, 0);
        }
        // M2a: oT = op(Sl, Q)
#pragma unroll
        for (int j = 0; j < 4; ++j) {
            bf16x8 y0 = ldsfrag(Qm, 16 * j + (lane & 15), 0, lane);
            bf16x8 y1 = ldsfrag(Qm, 16 * j + (lane & 15), 1, lane);
            oa[j] = __builtin_amdgcn_mfma_f32_16x16x32_bf16(xs0, y0, oa[j], 0, 0, 0);
            oa[j] = __builtin_amdgcn_mfma_f32_16x16x32_bf16(xs1, y1, oa[j], 0, 0, 0);
        }
        // finalize U^T = U0T - ut, write to wave-private LDS (bf16, swz)
#pragma unroll
        for (int j = 0; j < 4; ++j)
#pragma unroll
            for (int r = 0; r < 4; ++r) {
                int m = 16 * w + g * 4 + r;          // dv (global row in U0T)
                int n = (lane & 15) + 16 * j;        // t
                float u0 = bf2f(*(const unsigned short*)(U0m + swz(m * 128 + n * 2)));
                float u = u0 - ut[j][r];
                *(unsigned short*)(UTw + swz((g * 4 + r) * 128 + n * 2)) = f2bf(u);
            }
        // M2b + M3 (UT wave-private: no barrier needed; compiler orders ds ops)
        bf16x8 us0 = ldsfrag(UTw, lane & 15, 0, lane);
        bf16x8 us1 = ldsfrag(UTw, lane & 15, 1, lane);
#pragma unroll
        for (int j = 0; j < 4; ++j) {
            bf16x8 y0 = ldsfrag(Am, 16 * j + (lane & 15), 0, lane);
            bf16x8 y1 = ldsfrag(Am, 16 * j + (lane & 15), 1, lane);
            oa[j] = __builtin_amdgcn_mfma_f32_16x16x32_bf16(us0, y0, oa[j], 0, 0, 0);
            oa[j] = __builtin_amdgcn_mfma_f32_16x16x32_bf16(us1, y1, oa[j], 0, 0, 0);
        }
#pragma unroll
        for (int j = 0; j < 4; ++j) {
            bf16x8 y0 = ldsfrag(KTm, 16 * j + (lane & 15), 0, lane);
            bf16x8 y1 = ldsfrag(KTm, 16 * j + (lane & 15), 1, lane);
            s_acc[j] = __builtin_amdgcn_mfma_f32_16x16x32_bf16(us0, y0, s_acc[j], 0, 0, 0);
            s_acc[j] = __builtin_amdgcn_mfma_f32_16x16x32_bf16(us1, y1, s_acc[j], 0, 0, 0);
        }
        // o store: oT[dv][t] -> transposed packed global o[t][h*64+dv..+3] bf16
#pragma unroll
        for (int j = 0; j < 4; ++j) {
            int n = (lane & 15) + 16 * j;            // t local
            size_t tg = (size_t)b * SS + c * 64 + n;
            int col = h * 64 + 16 * w + g * 4;
            ushort4 pk;
            pk.x = f2bf(oa[j][0]); pk.y = f2bf(oa[j][1]);
            pk.z = f2bf(oa[j][2]); pk.w = f2bf(oa[j][3]);
            *(ushort4*)(ob + tg * DD + col) = pk;
        }
        // refresh bf16 S mirror from fp32 accs (wave-private)
#pragma unroll
        for (int j = 0; j < 4; ++j)
#pragma unroll
            for (int r = 0; r < 4; ++r) {
                int n = (lane & 15) + 16 * j;        // dk
                *(unsigned short*)(Slw + swz((g * 4 + r) * 128 + n * 2)) = f2bf(s_acc[j][r]);
            }

        asm volatile("" ::: "memory");
        __builtin_amdgcn_s_barrier();   // all waves done reading cur before it is re-staged
        __builtin_amdgcn_sched_barrier(0);
    }
}

// ---------------- launch ----------------
extern "C" void kernel_launch(void* const* d_in, const int* in_sizes, int n_in,
                              void* d_out, int out_size, void* d_ws, size_t ws_size,
                              hipStream_t stream) {
    const float* hidden = (const float*)d_in[0];
    const float* Wq  = (const float*)d_in[1];
    const float* Wk  = (const float*)d_in[2];
    const float* Wv  = (const float*)d_in[3];
    const float* Wb  = (const float*)d_in[4];
    const float* Wo  = (const float*)d_in[5];
    const float* ln1 = (const float*)d_in[6];
    const float* ln2 = (const float*)d_in[7];
    const float* Wg  = (const float*)d_in[8];
    const float* Wu  = (const float*)d_in[9];
    const float* Wd  = (const float*)d_in[10];
    float* out = (float*)d_out;
    char* ws = (char*)d_ws;

    const size_t MB = 1024 * 1024;
    const size_t KB256 = 262144;
    // QKV+beta Bt: rows 0..1023 wq | 1024..2047 wk | 2048..3071 wv | 3072..3199 WbT(+pad)
    unsigned short* wq_t = (unsigned short*)(ws + 0 * MB);              // 2MB
    unsigned short* wk_t = (unsigned short*)(ws + 2 * MB);              // 2MB
    unsigned short* wv_t = (unsigned short*)(ws + 4 * MB);              // 2MB
    unsigned short* wbT  = (unsigned short*)(ws + 6 * MB);              // 0.25MB
    unsigned short* wo_t = (unsigned short*)(ws + 6 * MB + KB256);      // 2MB
    unsigned short* btGU = (unsigned short*)(ws + 8 * MB + KB256);      // 16MB interleaved [8192][1024]
    unsigned short* wd_t = (unsigned short*)(ws + 24 * MB + KB256);     // 8MB
    float* hbuf          = (float*)(ws + 32 * MB + KB256);              // 16MB fp32
    unsigned short* yb   = (unsigned short*)(ws + 48 * MB + KB256);     // 8MB
    unsigned short* qb   = (unsigned short*)(ws + 56 * MB + KB256);     // 8MB (q,k,v contiguous)
    unsigned short* kb   = (unsigned short*)(ws + 64 * MB + KB256);     // 8MB
    unsigned short* vb   = (unsigned short*)(ws + 72 * MB + KB256);     // 8MB
    float* betab         = (float*)(ws + 80 * MB + KB256);              // 0.25MB
    unsigned short* xb   = (unsigned short*)(ws + 80 * MB + 2 * KB256); // 8MB (dead after QKV gemm)
    unsigned short* ob   = xb;                                          // alias
    char* chunkbuf       = ws + 88 * MB + 2 * KB256;                    // 40MB -> 128.5MB total
    // act (32MB bf16 [4096][4096]): aliases qb..xb region (dead after delta/Wo)
    unsigned short* act  = (unsigned short*)(ws + 56 * MB + KB256);

    dim3 blk(256);

    // weights: fp32 [K][N] -> bf16 [N][K]
    transpose_cvt4<<<dim3(32, 32, 4), blk, 0, stream>>>(Wq, Wk, Wv, Wo, wq_t, wk_t, wv_t, wo_t);
    transpose_cvt_gu<<<dim3(128, 32, 2), blk, 0, stream>>>(Wg, Wu, btGU);
    transpose_cvt<<<dim3(32, 128), blk, 0, stream>>>(Wd, wd_t, FF, DD);
    wbt_kernel<<<64, blk, 0, stream>>>(Wb, wbT);

    rmsnorm_bf16_kernel<<<ROWS, blk, 0, stream>>>(hidden, ln1, xb);

    // fused Q/K/V/beta GEMM (pad cols 3088..3199 discarded in epilogue)
    gemm2<3, 128, 128, 2, 2, false><<<dim3((NQKV / 128) * (ROWS / 128)), blk, 0, stream>>>(
        xb, wq_t, nullptr, betab, qb, ROWS, NQKV, DD);

    delta_prep_kernel<<<1024, blk, 0, stream>>>(qb, kb, vb, betab, chunkbuf);
    delta_seq_kernel<<<BB * HH, blk, 0, stream>>>(chunkbuf, ob);

    gemm2<1, 128, 128, 2, 2, false><<<dim3((DD / 128) * (ROWS / 128)), blk, 0, stream>>>(
        ob, wo_t, hidden, hbuf, nullptr, ROWS, DD, DD);

    rmsnorm_bf16_kernel<<<ROWS, blk, 0, stream>>>(hbuf, ln2, yb);

    // merged G/U GEMM, 256x256 tile, fused silu*u epilogue -> act
    gemm2<4, 256, 256, 2, 4, true><<<dim3((2 * FF / 256) * (ROWS / 256)), dim3(512), 0, stream>>>(
        yb, btGU, nullptr, nullptr, act, ROWS, 2 * FF, DD);

    gemm2<1, 128, 128, 2, 2, false><<<dim3((DD / 128) * (ROWS / 128)), blk, 0, stream>>>(
        act, wd_t, hbuf, out, nullptr, ROWS, DD, FF);
}

// Round 5
// 456.068 us; speedup vs baseline: 4.3844x; 1.0179x over previous
//
#include <hip/hip_runtime.h>
#include <hip/hip_bf16.h>
#include <stdint.h>

// Problem constants (B,S,D,F,H fixed by the reference)
#define BB 2
#define SS 2048
#define DD 1024
#define FF 4096
#define HH 16
#define ROWS (BB*SS)   // 4096
#define NC 32          // chunks per (b,h)  (2048/64)
#define NQKV 3200      // 3*1024 (q,k,v) + 16 (beta) padded to mult of 128

typedef float f32x4 __attribute__((ext_vector_type(4)));
typedef __bf16 bf16x8 __attribute__((ext_vector_type(8)));

typedef __attribute__((address_space(1))) const void* gas1p;
typedef __attribute__((address_space(3))) void* las3p;

__device__ __forceinline__ void gload16(const void* g, void* l) {
    // wave-uniform LDS base; HW scatters lane i at base + i*16; global addr is per-lane
    __builtin_amdgcn_global_load_lds((gas1p)g, (las3p)l, 16, 0, 0);
}

__device__ __forceinline__ unsigned short f2bf(float f) {
    unsigned int u = __builtin_bit_cast(unsigned int, f);
    u += 0x7fffu + ((u >> 16) & 1u);   // round-to-nearest-even
    return (unsigned short)(u >> 16);
}
__device__ __forceinline__ float bf2f(unsigned short s) {
    unsigned int u = ((unsigned int)s) << 16;
    return __builtin_bit_cast(float, u);
}
__device__ __forceinline__ float sigmoidf_(float x) { return 1.f / (1.f + __expf(-x)); }
__device__ __forceinline__ float siluf_(float x)    { return x / (1.f + __expf(-x)); }

// XOR swizzle for 64x64 bf16 (128B-row) LDS tiles: spreads the 16-way bank conflict
__device__ __forceinline__ int swz(int b) { return b ^ (((b >> 7) & 7) << 4); }

// ---------------- transpose + fp32->bf16 convert: W[K][N] -> Wt[N][K] ----------------
__device__ __forceinline__ void tp_body(const float* __restrict__ W,
                                        unsigned short* __restrict__ Wt,
                                        int K, int N, int bx, int by, int tid) {
    __shared__ float tile[32][33];
    int tx = tid & 31, ty = tid >> 5; // ty 0..7
    int n0 = bx * 32, k0 = by * 32;
#pragma unroll
    for (int i = 0; i < 4; ++i)
        tile[ty + 8 * i][tx] = W[(size_t)(k0 + ty + 8 * i) * N + n0 + tx];
    __syncthreads();
#pragma unroll
    for (int i = 0; i < 4; ++i)
        Wt[(size_t)(n0 + ty + 8 * i) * K + k0 + tx] = f2bf(tile[tx][ty + 8 * i]);
}

__global__ __launch_bounds__(256) void transpose_cvt(const float* __restrict__ W,
                                                     unsigned short* __restrict__ Wt,
                                                     int K, int N) {
    tp_body(W, Wt, K, N, blockIdx.x, blockIdx.y, threadIdx.x);
}

// 4 same-shape (1024x1024) weights in one launch
__global__ __launch_bounds__(256) void transpose_cvt4(const float* W0, const float* W1,
                                                      const float* W2, const float* W3,
                                                      unsigned short* T0, unsigned short* T1,
                                                      unsigned short* T2, unsigned short* T3) {
    const float* W = (blockIdx.z == 0) ? W0 : (blockIdx.z == 1) ? W1 : (blockIdx.z == 2) ? W2 : W3;
    unsigned short* T = (blockIdx.z == 0) ? T0 : (blockIdx.z == 1) ? T1 : (blockIdx.z == 2) ? T2 : T3;
    tp_body(W, T, DD, DD, blockIdx.x, blockIdx.y, threadIdx.x);
}

// Wg/Wu (1024x4096) -> interleaved BtGU [8192][1024]:
// group gi (16 cols of F): rows 32gi..32gi+15 = Wg cols, rows 32gi+16..+31 = Wu cols
__global__ __launch_bounds__(256) void transpose_cvt_gu(const float* W0, const float* W1,
                                                        unsigned short* Wt) {
    const float* W = (blockIdx.z == 0) ? W0 : W1;
    int isU = blockIdx.z;
    __shared__ float tile[32][33];
    int tid = threadIdx.x;
    int tx = tid & 31, ty = tid >> 5;
    int n0 = blockIdx.x * 32, k0 = blockIdx.y * 32;
#pragma unroll
    for (int i = 0; i < 4; ++i)
        tile[ty + 8 * i][tx] = W[(size_t)(k0 + ty + 8 * i) * FF + n0 + tx];
    __syncthreads();
#pragma unroll
    for (int i = 0; i < 4; ++i) {
        int j = n0 + ty + 8 * i;
        int rint = ((j >> 4) << 5) + (j & 15) + (isU << 4);
        Wt[(size_t)rint * DD + k0 + tx] = f2bf(tile[tx][ty + 8 * i]);
    }
}

// Wb [1024][16] fp32 -> WbT [16][1024] bf16
__global__ __launch_bounds__(256) void wbt_kernel(const float* __restrict__ Wb,
                                                  unsigned short* __restrict__ WbT) {
    int idx = blockIdx.x * 256 + threadIdx.x;  // 0..16383
    int d = idx >> 4, h = idx & 15;
    WbT[h * DD + d] = f2bf(Wb[idx]);
}

// ---------------- RMSNorm (D=1024) -> bf16 ----------------
__global__ __launch_bounds__(256) void rmsnorm_bf16_kernel(const float* __restrict__ src,
                                                           const float* __restrict__ w,
                                                           unsigned short* __restrict__ dst) {
    int row = blockIdx.x;
    int tid = threadIdx.x;
    float4 x = ((const float4*)(src + (size_t)row * DD))[tid];
    float ss = x.x * x.x + x.y * x.y + x.z * x.z + x.w * x.w;
#pragma unroll
    for (int m = 1; m < 64; m <<= 1) ss += __shfl_xor(ss, m, 64);
    __shared__ float ws4[4];
    if ((tid & 63) == 0) ws4[tid >> 6] = ss;
    __syncthreads();
    ss = ws4[0] + ws4[1] + ws4[2] + ws4[3];
    float sc = rsqrtf(ss * (1.f / DD) + 1e-6f);
    float4 wv = ((const float4*)w)[tid];
    ushort4 o;
    o.x = f2bf(x.x * sc * wv.x);
    o.y = f2bf(x.y * sc * wv.y);
    o.z = f2bf(x.z * sc * wv.z);
    o.w = f2bf(x.w * sc * wv.w);
    ((ushort4*)(dst + (size_t)row * DD))[tid] = o;
}

// ---------------- 2-phase double-buffered bf16 GEMM (128x128 shapes) ----------------
// C[M][N] = A[M][K] * Bt[N][K]^T.  BK=64, dbuf LDS, one __syncthreads per K-step.
// EP 1: fp32 out + fp32 residual
// EP 2: bf16 out
// EP 3: fused QKV+beta split epilogue (cb = q|k|v bufs, cf = beta)
template <int EP, int BMt, int BNt, int WM, int WN, bool FASTM>
__global__ __launch_bounds__(WM * WN * 64) void gemm2(const unsigned short* __restrict__ A,
                                                      const unsigned short* __restrict__ Bt,
                                                      const float* __restrict__ res,
                                                      float* __restrict__ cf,
                                                      unsigned short* __restrict__ cb,
                                                      int M, int N, int K) {
    constexpr int NW = WM * WN;
    constexpr int MI = BMt / (WM * 16);
    constexpr int NI = BNt / (WN * 16);
    constexpr int ACH = BMt / 8 / NW;     // 1KB chunks per wave (A)
    constexpr int BCH = BNt / 8 / NW;
    constexpr int ABYTES = BMt * 128;     // one K-tile of A (BK=64 bf16 = 128B rows)
    constexpr int BBYTES = BNt * 128;
    __shared__ __align__(16) char lds[2 * (ABYTES + BBYTES)];

    int tid = threadIdx.x, lane = tid & 63, w = tid >> 6;
    int wm = w / WN, wn = w % WN;

    // bijective XCD-chunked swizzle (m204)
    int gm = M / BMt, gn = N / BNt, nwg = gm * gn;
    int flat = blockIdx.x;
    int q = nwg >> 3, r8 = nwg & 7;
    int xcd = flat & 7, loc = flat >> 3;
    int sid = (xcd < r8 ? xcd * (q + 1) : r8 * (q + 1) + (xcd - r8) * q) + loc;
    int midx, nidx;
    if (FASTM) { midx = sid % gm; nidx = sid / gm; }
    else       { nidx = sid % gn; midx = sid / gn; }
    int m0 = midx * BMt, n0 = nidx * BNt;

    auto stage = [&](int buf, int kt) {
        char* base = (char*)lds + buf * (ABYTES + BBYTES);
        int row8 = lane >> 3, col = (lane & 7) * 8;
#pragma unroll
        for (int i = 0; i < ACH; ++i) {
            int c = w * ACH + i;
            gload16(A + ((size_t)(m0 + c * 8 + row8) * K + kt * 64 + col), base + c * 1024);
        }
#pragma unroll
        for (int i = 0; i < BCH; ++i) {
            int c = w * BCH + i;
            gload16(Bt + ((size_t)(n0 + c * 8 + row8) * K + kt * 64 + col), base + ABYTES + c * 1024);
        }
    };

    f32x4 acc[MI][NI] = {};
    int nk = K / 64;
    stage(0, 0);
    __syncthreads();
    int cur = 0;
    for (int kt = 0; kt < nk; ++kt) {
        if (kt + 1 < nk) stage(cur ^ 1, kt + 1);   // async loads overlap this tile's MFMA
        const char* abuf = (const char*)lds + cur * (ABYTES + BBYTES);
        const char* bbuf = abuf + ABYTES;
#pragma unroll
        for (int kk = 0; kk < 2; ++kk) {
            bf16x8 afr[MI], bfr[NI];
#pragma unroll
            for (int mi = 0; mi < MI; ++mi)
                afr[mi] = *(const bf16x8*)(abuf + (wm * (MI * 16) + mi * 16 + (lane & 15)) * 128 + kk * 64 + (lane >> 4) * 16);
#pragma unroll
            for (int ni = 0; ni < NI; ++ni)
                bfr[ni] = *(const bf16x8*)(bbuf + (wn * (NI * 16) + ni * 16 + (lane & 15)) * 128 + kk * 64 + (lane >> 4) * 16);
#pragma unroll
            for (int mi = 0; mi < MI; ++mi)
#pragma unroll
                for (int ni = 0; ni < NI; ++ni)
                    acc[mi][ni] = __builtin_amdgcn_mfma_f32_16x16x32_bf16(afr[mi], bfr[ni], acc[mi][ni], 0, 0, 0);
        }
        if (kt + 1 < nk) {
            __syncthreads();   // drains vmcnt (staged tile ready) + all waves done reading cur
            cur ^= 1;
        }
    }

    int mbase = m0 + wm * (MI * 16) + (lane >> 4) * 4;
    int nbase = n0 + wn * (NI * 16) + (lane & 15);
#pragma unroll
    for (int mi = 0; mi < MI; ++mi)
#pragma unroll
        for (int ni = 0; ni < NI; ++ni)
#pragma unroll
            for (int r = 0; r < 4; ++r) {
                int m = mbase + mi * 16 + r;
                int n = nbase + ni * 16;
                float v = acc[mi][ni][r];
                if (EP == 3) {
                    int seg = n >> 10, col = n & 1023;
                    if (seg < 3)
                        cb[(size_t)seg * ROWS * DD + (size_t)m * DD + col] = f2bf(v);
                    else if (col < 16)
                        cf[(size_t)m * HH + col] = sigmoidf_(v);
                } else {
                    if (EP == 1) v += res[(size_t)m * N + n];
                    if (EP == 2) cb[(size_t)m * N + n] = f2bf(v);
                    else         cf[(size_t)m * N + n] = v;
                }
            }
}

// ---------------- 8-phase-style 256x256 GEMM with counted vmcnt (GU fused) ----------------
// BK=32 K-tiles in a 4-slot LDS ring (32KB each: A 16KB | B 16KB). Staging runs 3 tiles
// ahead (phase0: A of kt+3, phase1: B of kt+3) into slot (kt+3)&3 = (kt-1)&3 whose reads
// finished at the previous tile boundary. Boundary wait: vmcnt(8) -> tiles kt+1/kt+2's 8
// loads stay in flight across barriers (T4). LDS swizzle: byte bits[4:5] ^= row&3 via
// pre-swizzled global source + swizzled ds_read (both-sides, rule 21). T5 setprio on MFMA.
// Epilogue: Bt rows are 16-interleaved g/u -> act[m][f] = silu(g)*u bf16.
__global__ __launch_bounds__(512, 2) void gemm8_gu(const unsigned short* __restrict__ A,
                                                   const unsigned short* __restrict__ Bt,
                                                   unsigned short* __restrict__ cb,
                                                   int M, int N, int K) {
    __shared__ __align__(16) char lds8[4 * 32768];
    int tid = threadIdx.x, lane = tid & 63, w = tid >> 6;
    int wm = w >> 2, wn = w & 3;   // 2M x 4N waves; per-wave C = 128 x 64

    int gm = M / 256, gn = N / 256, nwg = gm * gn;
    int flat = blockIdx.x;
    int q = nwg >> 3, r8 = nwg & 7;
    int xcd = flat & 7, loc = flat >> 3;
    int sid = (xcd < r8 ? xcd * (q + 1) : r8 * (q + 1) + (xcd - r8) * q) + loc;
    int midx = sid % gm, nidx = sid / gm;   // M-fast within XCD chunk: B-panel L2 reuse
    int m0 = midx * 256, n0 = nidx * 256;

    int rl = tid >> 2;                          // staging row 0..127 (+128 for 2nd load)
    int sc = ((tid & 3) ^ (rl & 3)) * 8;        // pre-swizzled source col (bf16 elems)
    auto stA = [&](int kt) {
        char* dst = lds8 + (kt & 3) * 32768;
        const unsigned short* src = A + (size_t)(m0 + rl) * K + kt * 32 + sc;
        gload16(src, dst + tid * 16);
        gload16(src + (size_t)128 * K, dst + 8192 + tid * 16);
    };
    auto stB = [&](int kt) {
        char* dst = lds8 + (kt & 3) * 32768 + 16384;
        const unsigned short* src = Bt + (size_t)(n0 + rl) * K + kt * 32 + sc;
        gload16(src, dst + tid * 16);
        gload16(src + (size_t)128 * K, dst + 8192 + tid * 16);
    };
    auto rdA = [&](const char* Ab, int mi) -> bf16x8 {
        int b = (wm * 128 + mi * 16 + (lane & 15)) * 64 + (lane >> 4) * 16;
        return *(const bf16x8*)(Ab + (b ^ (((b >> 6) & 3) << 4)));
    };
    auto rdB = [&](const char* Bb, int ni) -> bf16x8 {
        int b = (wn * 64 + ni * 16 + (lane & 15)) * 64 + (lane >> 4) * 16;
        return *(const bf16x8*)(Bb + (b ^ (((b >> 6) & 3) << 4)));
    };

    f32x4 acc[8][4] = {};
    int nk = K / 32;

    // prologue: stage tiles 0,1,2 into slots 0,1,2 (12 loads in flight)
    stA(0); stB(0); stA(1); stB(1); stA(2); stB(2);

    for (int kt = 0; kt < nk; ++kt) {
        // counted-vmcnt tile boundary: allow tiles kt+1, kt+2's 8 loads to stay in flight
        int rem = nk - 1 - kt;
        if (rem >= 2)      asm volatile("s_waitcnt vmcnt(8)" ::: "memory");
        else if (rem == 1) asm volatile("s_waitcnt vmcnt(4)" ::: "memory");
        else               asm volatile("s_waitcnt vmcnt(0)" ::: "memory");
        __builtin_amdgcn_s_barrier();           // all waves drained -> slot kt&3 complete
        __builtin_amdgcn_sched_barrier(0);      // pin ds_reads below the barrier
        const char* Ab = lds8 + (kt & 3) * 32768;
        const char* Bb = Ab + 16384;

        bf16x8 bfr[4];
        // ---- phase 0: m-frags 0..3 x all n ----
        {
            bf16x8 af[4];
#pragma unroll
            for (int mi = 0; mi < 4; ++mi) af[mi] = rdA(Ab, mi);
#pragma unroll
            for (int ni = 0; ni < 4; ++ni) bfr[ni] = rdB(Bb, ni);
            if (kt + 3 < nk) stA(kt + 3);
            __builtin_amdgcn_s_barrier();
            __builtin_amdgcn_s_setprio(1);
#pragma unroll
            for (int mi = 0; mi < 4; ++mi)
#pragma unroll
                for (int ni = 0; ni < 4; ++ni)
                    acc[mi][ni] = __builtin_amdgcn_mfma_f32_16x16x32_bf16(af[mi], bfr[ni], acc[mi][ni], 0, 0, 0);
            __builtin_amdgcn_s_setprio(0);
            __builtin_amdgcn_s_barrier();
        }
        // ---- phase 1: m-frags 4..7 x all n ----
        {
            bf16x8 af[4];
#pragma unroll
            for (int mi = 0; mi < 4; ++mi) af[mi] = rdA(Ab, mi + 4);
            if (kt + 3 < nk) stB(kt + 3);
            __builtin_amdgcn_s_barrier();
            __builtin_amdgcn_s_setprio(1);
#pragma unroll
            for (int mi = 0; mi < 4; ++mi)
#pragma unroll
                for (int ni = 0; ni < 4; ++ni)
                    acc[mi + 4][ni] = __builtin_amdgcn_mfma_f32_16x16x32_bf16(af[mi], bfr[ni], acc[mi + 4][ni], 0, 0, 0);
            __builtin_amdgcn_s_setprio(0);
            // trailing barrier of this tile = next iteration's boundary barrier
        }
    }

    // fused GU epilogue: ni pairs (2p, 2p+1) = (g,u) of the same f 16-col group
    int j0 = (n0 + wn * 64) / 2 + (lane & 15);
    int mb = m0 + wm * 128 + (lane >> 4) * 4;
#pragma unroll
    for (int mi = 0; mi < 8; ++mi)
#pragma unroll
        for (int p = 0; p < 2; ++p)
#pragma unroll
            for (int r = 0; r < 4; ++r) {
                int m = mb + mi * 16 + r;
                float gv = acc[mi][2 * p][r], uv = acc[mi][2 * p + 1][r];
                cb[(size_t)m * FF + j0 + 16 * p] = f2bf(siluf_(gv) * uv);
            }
}

// ================= chunked delta rule =================
// Per-chunk matrices are 64x64. MFMA op(X,Y)[m][n] = sum_k X[m][k]*Y[n][k]
// (both operands read row-major, [idx][k], idx = lane&15).
// D-layout: n = lane&15, m = 16*tile_m + (lane>>4)*4 + r.

__device__ __forceinline__ bf16x8 ldsfrag(const char* mat, int row, int kt, int lane) {
    return *(const bf16x8*)(mat + swz(row * 128 + kt * 64 + (lane >> 4) * 16));
}

// generic 64x64x64 matmul on swizzled LDS bf16 matrices; wave w owns m-rows [16w,16w+16)
template <bool INIT_P>
__device__ __forceinline__ void mm64(const char* X, const char* Y, const char* P,
                                     f32x4 acc[4], int w, int lane) {
    int g = lane >> 4;
#pragma unroll
    for (int j = 0; j < 4; ++j) {
        if (INIT_P) {
#pragma unroll
            for (int r = 0; r < 4; ++r) {
                int m = 16 * w + g * 4 + r, n = (lane & 15) + 16 * j;
                acc[j][r] = bf2f(*(const unsigned short*)(P + swz(m * 128 + n * 2)));
            }
        } else {
            acc[j] = (f32x4){0.f, 0.f, 0.f, 0.f};
        }
    }
    bf16x8 xs0 = ldsfrag(X, 16 * w + (lane & 15), 0, lane);
    bf16x8 xs1 = ldsfrag(X, 16 * w + (lane & 15), 1, lane);
#pragma unroll
    for (int j = 0; j < 4; ++j) {
        bf16x8 y0 = ldsfrag(Y, 16 * j + (lane & 15), 0, lane);
        bf16x8 y1 = ldsfrag(Y, 16 * j + (lane & 15), 1, lane);
        acc[j] = __builtin_amdgcn_mfma_f32_16x16x32_bf16(xs0, y0, acc[j], 0, 0, 0);
        acc[j] = __builtin_amdgcn_mfma_f32_16x16x32_bf16(xs1, y1, acc[j], 0, 0, 0);
    }
}

// row-major LDS write. mode: 0 plain, 1 strict-lower (keep n<m), 2 P1 = I - strict(L)
__device__ __forceinline__ void wR(char* D, const f32x4 acc[4], int w, int lane, int mode) {
    int g = lane >> 4;
#pragma unroll
    for (int j = 0; j < 4; ++j)
#pragma unroll
        for (int r = 0; r < 4; ++r) {
            int m = 16 * w + g * 4 + r, n = (lane & 15) + 16 * j;
            float v = acc[j][r];
            if (mode >= 1) v = (n < m) ? v : 0.f;
            if (mode == 2) v = ((m == n) ? 1.f : 0.f) - v;
            *(unsigned short*)(D + swz(m * 128 + n * 2)) = f2bf(v);
        }
}

// transposed packed LDS write: D[n][m0..m0+3]. mode: 0 plain, 1 strict (keep n<m)
__device__ __forceinline__ void wT(char* D, const f32x4 acc[4], int w, int lane, int mode) {
    int g = lane >> 4;
#pragma unroll
    for (int j = 0; j < 4; ++j) {
        int n = (lane & 15) + 16 * j, m0 = 16 * w + g * 4;
        ushort4 pk;
        pk.x = (mode == 1 && !(n < m0 + 0)) ? (unsigned short)0 : f2bf(acc[j][0]);
        pk.y = (mode == 1 && !(n < m0 + 1)) ? (unsigned short)0 : f2bf(acc[j][1]);
        pk.z = (mode == 1 && !(n < m0 + 2)) ? (unsigned short)0 : f2bf(acc[j][2]);
        pk.w = (mode == 1 && !(n < m0 + 3)) ? (unsigned short)0 : f2bf(acc[j][3]);
        *(ushort4*)(D + swz(n * 128 + m0 * 2)) = pk;
    }
}

__device__ __forceinline__ void load16bf(const unsigned short* p, float* v) {
    uint4 a = *(const uint4*)p, b = *(const uint4*)(p + 8);
    unsigned int u0[8] = {a.x, a.y, a.z, a.w, b.x, b.y, b.z, b.w};
#pragma unroll
    for (int i = 0; i < 8; ++i) {
        v[2 * i]     = bf2f((unsigned short)(u0[i] & 0xffffu));
        v[2 * i + 1] = bf2f((unsigned short)(u0[i] >> 16));
    }
}

// -------- parallel per-chunk prep: silu/l2norm/beta-scale + T=(I+L)^-1 + outputs --------
__global__ __launch_bounds__(256) void delta_prep_kernel(const unsigned short* __restrict__ qb,
                                                         const unsigned short* __restrict__ kb,
                                                         const unsigned short* __restrict__ vb,
                                                         const float* __restrict__ betab,
                                                         char* __restrict__ chunkbuf) {
    __shared__ __align__(16) char sK[8192], sKb[8192], sKbT[8192], sVbT[8192], sQ[8192];
    __shared__ __align__(16) char mA[8192], mAT[8192], mB2[8192], mBT[8192], mP0[8192], mP1[8192];

    int ci = blockIdx.x;
    int c = ci & 31, h = (ci >> 5) & 15, b = ci >> 9;
    int tid = threadIdx.x;
    int lane = tid & 63, w = tid >> 6;

    char* cbuf = chunkbuf + (size_t)ci * 40960;
    unsigned short* Qg  = (unsigned short*)(cbuf);
    unsigned short* KTg = (unsigned short*)(cbuf + 8192);
    unsigned short* Ag  = (unsigned short*)(cbuf + 16384);
    unsigned short* Wg  = (unsigned short*)(cbuf + 24576);
    unsigned short* U0g = (unsigned short*)(cbuf + 32768);

    // ---- staging: 4 threads per row, 16 elems each ----
    {
        int trow = tid >> 2, part = tid & 3, d0 = part * 16;
        size_t rg = (size_t)b * SS + c * 64 + trow;
        float bet = betab[rg * HH + h];
        size_t base = rg * DD + h * 64 + d0;

        float qv[16], kv[16], vv[16];
        load16bf(qb + base, qv);
        load16bf(kb + base, kv);
        load16bf(vb + base, vv);

        float ssq = 0.f, ssk = 0.f;
#pragma unroll
        for (int i = 0; i < 16; ++i) {
            qv[i] = siluf_(qv[i]); ssq += qv[i] * qv[i];
            kv[i] = siluf_(kv[i]); ssk += kv[i] * kv[i];
            vv[i] = siluf_(vv[i]);
        }
        ssq += __shfl_xor(ssq, 1, 64); ssq += __shfl_xor(ssq, 2, 64);
        ssk += __shfl_xor(ssk, 1, 64); ssk += __shfl_xor(ssk, 2, 64);
        float scq = rsqrtf(ssq + 1e-6f), sck = rsqrtf(ssk + 1e-6f);
#pragma unroll
        for (int i = 0; i < 16; ++i) { qv[i] *= scq; kv[i] *= sck; }

        // packed swizzled LDS writes (4x ushort4 per matrix) + global Q
#pragma unroll
        for (int m = 0; m < 4; ++m) {
            ushort4 pq, pk_, pkb;
#pragma unroll
            for (int r = 0; r < 4; ++r) {
                ((unsigned short*)&pq)[r]  = f2bf(qv[4 * m + r]);
                ((unsigned short*)&pk_)[r] = f2bf(kv[4 * m + r]);
                ((unsigned short*)&pkb)[r] = f2bf(bet * kv[4 * m + r]);
            }
            int bo = trow * 128 + (d0 + 4 * m) * 2;
            *(ushort4*)(sQ + swz(bo))  = pq;
            *(ushort4*)(sK + swz(bo))  = pk_;
            *(ushort4*)(sKb + swz(bo)) = pkb;
            *(ushort4*)(Qg + trow * 64 + d0 + 4 * m) = pq;
        }
        // scalar transposed writes: KbT, VbT (LDS), KT (global)
#pragma unroll
        for (int e = 0; e < 16; ++e) {
            int d = d0 + e;
            *(unsigned short*)(sKbT + swz(d * 128 + trow * 2)) = f2bf(bet * kv[e]);
            *(unsigned short*)(sVbT + swz(d * 128 + trow * 2)) = f2bf(bet * vv[e]);
            KTg[d * 64 + trow] = f2bf(kv[e]);
        }
    }
    __syncthreads();

    f32x4 acc[4];
    // L = strict_tril(K_b K^T); P1 = I - L
    mm64<false>(sKb, sK, nullptr, acc, w, lane);
    wR(mA, acc, w, lane, 1);   // L
    wT(mAT, acc, w, lane, 1);  // L^T
    wR(mP0, acc, w, lane, 2);  // P1
    __syncthreads();

    // T = (I-L)(I+L^2)(I+L^4)(I+L^8)(I+L^16)(I+L^32)
    char *cX = mA, *cXT = mAT, *nX = mB2, *nXT = mBT, *pc = mP0, *pn = mP1;
#pragma unroll
    for (int s = 0; s < 5; ++s) {
        mm64<false>(cX, cXT, nullptr, acc, w, lane);   // next power = cur^2
        wR(nX, acc, w, lane, 0);
        wT(nXT, acc, w, lane, 0);
        __syncthreads();
        mm64<true>(pc, nXT, pc, acc, w, lane);         // P = P + P * power
        wR(pn, acc, w, lane, 0);
        __syncthreads();
        char* t;
        t = cX; cX = nX; nX = t;
        t = cXT; cXT = nXT; nXT = t;
        t = pc; pc = pn; pn = t;
    }
    // pc now holds T

    int g = lane >> 4;
    // A = incl_tril(Q K^T): R = op(K, Q) -> write transposed packed to global, keep s<=t
    mm64<false>(sK, sQ, nullptr, acc, w, lane);
#pragma unroll
    for (int j = 0; j < 4; ++j) {
        int n = (lane & 15) + 16 * j, m0 = 16 * w + g * 4;  // n=t, m=s
        ushort4 pk;
        pk.x = (m0 + 0 <= n) ? f2bf(acc[j][0]) : (unsigned short)0;
        pk.y = (m0 + 1 <= n) ? f2bf(acc[j][1]) : (unsigned short)0;
        pk.z = (m0 + 2 <= n) ? f2bf(acc[j][2]) : (unsigned short)0;
        pk.w = (m0 + 3 <= n) ? f2bf(acc[j][3]) : (unsigned short)0;
        *(ushort4*)(Ag + n * 64 + m0) = pk;
    }
    // W = T*K_b: R = op(KbT, T) gives W^T -> transposed write = W[t][dk]
    mm64<false>(sKbT, pc, nullptr, acc, w, lane);
#pragma unroll
    for (int j = 0; j < 4; ++j) {
        int n = (lane & 15) + 16 * j, m0 = 16 * w + g * 4;  // n=t, m=dk
        ushort4 pk;
        pk.x = f2bf(acc[j][0]); pk.y = f2bf(acc[j][1]);
        pk.z = f2bf(acc[j][2]); pk.w = f2bf(acc[j][3]);
        *(ushort4*)(Wg + n * 64 + m0) = pk;
    }
    // U0 = T*V_b: R = op(T, VbT) = U0[t][dv] -> transposed write = U0T[dv][t]
    mm64<false>(pc, sVbT, nullptr, acc, w, lane);
#pragma unroll
    for (int j = 0; j < 4; ++j) {
        int n = (lane & 15) + 16 * j, m0 = 16 * w + g * 4;  // n=dv, m=t
        ushort4 pk;
        pk.x = f2bf(acc[j][0]); pk.y = f2bf(acc[j][1]);
        pk.z = f2bf(acc[j][2]); pk.w = f2bf(acc[j][3]);
        *(ushort4*)(U0g + n * 64 + m0) = pk;
    }
}

// -------- sequential inter-chunk scan: 32 blocks = (b,h), 256 threads --------
__global__ __launch_bounds__(256) void delta_seq_kernel(const char* __restrict__ chunkbuf,
                                                        unsigned short* __restrict__ ob) {
    __shared__ __align__(16) char stg[2 * 40960 + 8192 + 8192];
    int bh = blockIdx.x;
    int b = bh >> 4, h = bh & 15;
    int tid = threadIdx.x;
    int lane = tid & 63, w = tid >> 6, g = lane >> 4;

    char* UTw = stg + 81920 + w * 2048;   // wave-private U^T slice [16][64] bf16 swz
    char* Slw = stg + 90112 + w * 2048;   // wave-private S^T slice [16][64] bf16 swz

    // zero S
    f32x4 s_acc[4];
#pragma unroll
    for (int j = 0; j < 4; ++j) s_acc[j] = (f32x4){0.f, 0.f, 0.f, 0.f};
    uint4 z4 = {0, 0, 0, 0};
    *(uint4*)(Slw + lane * 32) = z4;
    *(uint4*)(Slw + lane * 32 + 16) = z4;

    const char* cbase = chunkbuf + (size_t)bh * NC * 40960;
    int lo = (lane * 16) ^ ((lane >> 3) << 4);   // pre-swizzled source offset per lane
    int pw = 10 * w;

    // prologue: stage chunk 0 into buffer 0
    {
        const char* src = cbase;
        char* dst = stg;
#pragma unroll
        for (int p = 0; p < 10; ++p)
            gload16(src + (pw + p) * 1024 + lo, dst + (pw + p) * 1024);
    }

    for (int c = 0; c < NC; ++c) {
        // issue prefetch for next chunk (wraps harmlessly at c=31)
        {
            const char* src = cbase + (size_t)((c + 1) & 31) * 40960;
            char* dst = stg + ((c + 1) & 1) * 40960;
#pragma unroll
            for (int p = 0; p < 10; ++p)
                gload16(src + (pw + p) * 1024 + lo, dst + (pw + p) * 1024);
        }
        asm volatile("s_waitcnt vmcnt(10)" ::: "memory");
        __builtin_amdgcn_s_barrier();
        __builtin_amdgcn_sched_barrier(0);

        const char* cur = stg + (c & 1) * 40960;
        const char* Qm = cur, *KTm = cur + 8192, *Am = cur + 16384, *Wm = cur + 24576, *U0m = cur + 32768;

        // X-frags from wave-private S^T
        bf16x8 xs0 = ldsfrag(Slw, lane & 15, 0, lane);
        bf16x8 xs1 = ldsfrag(Slw, lane & 15, 1, lane);

        // M1: ut = op(Sl, W)   (to be subtracted from U0T)
        f32x4 ut[4];
        f32x4 oa[4];
#pragma unroll
        for (int j = 0; j < 4; ++j) { ut[j] = (f32x4){0.f, 0.f, 0.f, 0.f}; oa[j] = (f32x4){0.f, 0.f, 0.f, 0.f}; }
#pragma unroll
        for (int j = 0; j < 4; ++j) {
            bf16x8 y0 = ldsfrag(Wm, 16 * j + (lane & 15), 0, lane);
            bf16x8 y1 = ldsfrag(Wm, 16 * j + (lane & 15), 1, lane);
            ut[j] = __builtin_amdgcn_mfma_f32_16x16x32_bf16(xs0, y0, ut[j], 0, 0, 0);
            ut[j] = __builtin_amdgcn_mfma_f32_16x16x32_bf16(xs1, y1, ut[j], 0, 0, 0);
        }
        // M2a: oT = op(Sl, Q)
#pragma unroll
        for (int j = 0; j < 4; ++j) {
            bf16x8 y0 = ldsfrag(Qm, 16 * j + (lane & 15), 0, lane);
            bf16x8 y1 = ldsfrag(Qm, 16 * j + (lane & 15), 1, lane);
            oa[j] = __builtin_amdgcn_mfma_f32_16x16x32_bf16(xs0, y0, oa[j], 0, 0, 0);
            oa[j] = __builtin_amdgcn_mfma_f32_16x16x32_bf16(xs1, y1, oa[j], 0, 0, 0);
        }
        // finalize U^T = U0T - ut, write to wave-private LDS (bf16, swz)
#pragma unroll
        for (int j = 0; j < 4; ++j)
#pragma unroll
            for (int r = 0; r < 4; ++r) {
                int m = 16 * w + g * 4 + r;          // dv (global row in U0T)
                int n = (lane & 15) + 16 * j;        // t
                float u0 = bf2f(*(const unsigned short*)(U0m + swz(m * 128 + n * 2)));
                float u = u0 - ut[j][r];
                *(unsigned short*)(UTw + swz((g * 4 + r) * 128 + n * 2)) = f2bf(u);
            }
        // M2b + M3 (UT wave-private: no barrier needed; compiler orders ds ops)
        bf16x8 us0 = ldsfrag(UTw, lane & 15, 0, lane);
        bf16x8 us1 = ldsfrag(UTw, lane & 15, 1, lane);
#pragma unroll
        for (int j = 0; j < 4; ++j) {
            bf16x8 y0 = ldsfrag(Am, 16 * j + (lane & 15), 0, lane);
            bf16x8 y1 = ldsfrag(Am, 16 * j + (lane & 15), 1, lane);
            oa[j] = __builtin_amdgcn_mfma_f32_16x16x32_bf16(us0, y0, oa[j], 0, 0, 0);
            oa[j] = __builtin_amdgcn_mfma_f32_16x16x32_bf16(us1, y1, oa[j], 0, 0, 0);
        }
#pragma unroll
        for (int j = 0; j < 4; ++j) {
            bf16x8 y0 = ldsfrag(KTm, 16 * j + (lane & 15), 0, lane);
            bf16x8 y1 = ldsfrag(KTm, 16 * j + (lane & 15), 1, lane);
            s_acc[j] = __builtin_amdgcn_mfma_f32_16x16x32_bf16(us0, y0, s_acc[j], 0, 0, 0);
            s_acc[j] = __builtin_amdgcn_mfma_f32_16x16x32_bf16(us1, y1, s_acc[j], 0, 0, 0);
        }
        // o store: oT[dv][t] -> transposed packed global o[t][h*64+dv..+3] bf16
#pragma unroll
        for (int j = 0; j < 4; ++j) {
            int n = (lane & 15) + 16 * j;            // t local
            size_t tg = (size_t)b * SS + c * 64 + n;
            int col = h * 64 + 16 * w + g * 4;
            ushort4 pk;
            pk.x = f2bf(oa[j][0]); pk.y = f2bf(oa[j][1]);
            pk.z = f2bf(oa[j][2]); pk.w = f2bf(oa[j][3]);
            *(ushort4*)(ob + tg * DD + col) = pk;
        }
        // refresh bf16 S mirror from fp32 accs (wave-private)
#pragma unroll
        for (int j = 0; j < 4; ++j)
#pragma unroll
            for (int r = 0; r < 4; ++r) {
                int n = (lane & 15) + 16 * j;        // dk
                *(unsigned short*)(Slw + swz((g * 4 + r) * 128 + n * 2)) = f2bf(s_acc[j][r]);
            }

        asm volatile("" ::: "memory");
        __builtin_amdgcn_s_barrier();   // all waves done reading cur before it is re-staged
        __builtin_amdgcn_sched_barrier(0);
    }
}

// ---------------- launch ----------------
extern "C" void kernel_launch(void* const* d_in, const int* in_sizes, int n_in,
                              void* d_out, int out_size, void* d_ws, size_t ws_size,
                              hipStream_t stream) {
    const float* hidden = (const float*)d_in[0];
    const float* Wq  = (const float*)d_in[1];
    const float* Wk  = (const float*)d_in[2];
    const float* Wv  = (const float*)d_in[3];
    const float* Wb  = (const float*)d_in[4];
    const float* Wo  = (const float*)d_in[5];
    const float* ln1 = (const float*)d_in[6];
    const float* ln2 = (const float*)d_in[7];
    const float* Wg  = (const float*)d_in[8];
    const float* Wu  = (const float*)d_in[9];
    const float* Wd  = (const float*)d_in[10];
    float* out = (float*)d_out;
    char* ws = (char*)d_ws;

    const size_t MB = 1024 * 1024;
    const size_t KB256 = 262144;
    // QKV+beta Bt: rows 0..1023 wq | 1024..2047 wk | 2048..3071 wv | 3072..3199 WbT(+pad)
    unsigned short* wq_t = (unsigned short*)(ws + 0 * MB);              // 2MB
    unsigned short* wk_t = (unsigned short*)(ws + 2 * MB);              // 2MB
    unsigned short* wv_t = (unsigned short*)(ws + 4 * MB);              // 2MB
    unsigned short* wbT  = (unsigned short*)(ws + 6 * MB);              // 0.25MB
    unsigned short* wo_t = (unsigned short*)(ws + 6 * MB + KB256);      // 2MB
    unsigned short* btGU = (unsigned short*)(ws + 8 * MB + KB256);      // 16MB interleaved [8192][1024]
    unsigned short* wd_t = (unsigned short*)(ws + 24 * MB + KB256);     // 8MB
    float* hbuf          = (float*)(ws + 32 * MB + KB256);              // 16MB fp32
    unsigned short* yb   = (unsigned short*)(ws + 48 * MB + KB256);     // 8MB
    unsigned short* qb   = (unsigned short*)(ws + 56 * MB + KB256);     // 8MB (q,k,v contiguous)
    unsigned short* kb   = (unsigned short*)(ws + 64 * MB + KB256);     // 8MB
    unsigned short* vb   = (unsigned short*)(ws + 72 * MB + KB256);     // 8MB
    float* betab         = (float*)(ws + 80 * MB + KB256);              // 0.25MB
    unsigned short* xb   = (unsigned short*)(ws + 80 * MB + 2 * KB256); // 8MB (dead after QKV gemm)
    unsigned short* ob   = xb;                                          // alias
    char* chunkbuf       = ws + 88 * MB + 2 * KB256;                    // 40MB -> 128.5MB total
    // act (32MB bf16 [4096][4096]): aliases qb..xb region (dead after delta/Wo)
    unsigned short* act  = (unsigned short*)(ws + 56 * MB + KB256);

    dim3 blk(256);

    // weights: fp32 [K][N] -> bf16 [N][K]
    transpose_cvt4<<<dim3(32, 32, 4), blk, 0, stream>>>(Wq, Wk, Wv, Wo, wq_t, wk_t, wv_t, wo_t);
    transpose_cvt_gu<<<dim3(128, 32, 2), blk, 0, stream>>>(Wg, Wu, btGU);
    transpose_cvt<<<dim3(32, 128), blk, 0, stream>>>(Wd, wd_t, FF, DD);
    wbt_kernel<<<64, blk, 0, stream>>>(Wb, wbT);

    rmsnorm_bf16_kernel<<<ROWS, blk, 0, stream>>>(hidden, ln1, xb);

    // fused Q/K/V/beta GEMM (pad cols 3088..3199 discarded in epilogue)
    gemm2<3, 128, 128, 2, 2, false><<<dim3((NQKV / 128) * (ROWS / 128)), blk, 0, stream>>>(
        xb, wq_t, nullptr, betab, qb, ROWS, NQKV, DD);

    delta_prep_kernel<<<1024, blk, 0, stream>>>(qb, kb, vb, betab, chunkbuf);
    delta_seq_kernel<<<BB * HH, blk, 0, stream>>>(chunkbuf, ob);

    gemm2<1, 128, 128, 2, 2, false><<<dim3((DD / 128) * (ROWS / 128)), blk, 0, stream>>>(
        ob, wo_t, hidden, hbuf, nullptr, ROWS, DD, DD);

    rmsnorm_bf16_kernel<<<ROWS, blk, 0, stream>>>(hbuf, ln2, yb);

    // merged G/U GEMM: 8-phase-style 256x256, counted vmcnt, fused silu*u epilogue -> act
    gemm8_gu<<<dim3((ROWS / 256) * (2 * FF / 256)), dim3(512), 0, stream>>>(
        yb, btGU, act, ROWS, 2 * FF, DD);

    gemm2<1, 128, 128, 2, 2, false><<<dim3((DD / 128) * (ROWS / 128)), blk, 0, stream>>>(
        act, wd_t, hbuf, out, nullptr, ROWS, DD, FF);
}